// Round 4
// baseline (3227.094 us; speedup 1.0000x reference)
//
#include <hip/hip_runtime.h>

typedef unsigned short u16;
typedef u16 u16x8 __attribute__((ext_vector_type(8)));
typedef __bf16 bf16x8 __attribute__((ext_vector_type(8)));
typedef float floatx4 __attribute__((ext_vector_type(4)));

#define N_EMBD 1024
#define N_HEAD 16
#define HEAD_DIM 64
#define SEQ 2048
#define BATCH 2
#define M_ROWS (BATCH * SEQ)  // 4096

__device__ __forceinline__ float bf2f(u16 b) {
  return __uint_as_float(((unsigned)b) << 16);
}
__device__ __forceinline__ u16 f2bf(float f) {
  unsigned u = __float_as_uint(f);
  u += 0x7fffu + ((u >> 16) & 1u);  // RNE
  return (u16)(u >> 16);
}

// ======== QKV GEMM: x_f32[M,1024] @ w_attn_f32[1024,3072] + b_attn ========
// scatters bf16 into q/k/v [B,H,T,D].  Scratch: only q/k/v (24 MB total).
#define BM 64
#define BN 64
#define BK 32

__global__ __launch_bounds__(256) void qkv_gemm(const float* __restrict__ X,
                                                const float* __restrict__ W,
                                                const float* __restrict__ bias,
                                                u16* __restrict__ qo,
                                                u16* __restrict__ ko,
                                                u16* __restrict__ vo) {
  __shared__ u16 As[BM * BK];  // [m][k]
  __shared__ u16 Bs[BN * BK];  // [n][k]
  const int tid = threadIdx.x;
  const int bm = blockIdx.y * BM;
  const int bn = blockIdx.x * BN;  // 0..3008
  const int w = tid >> 6;
  const int l = tid & 63;
  const int wm = (w >> 1) * 32;
  const int wn = (w & 1) * 32;
  const int m16 = l & 15;
  const int quad = l >> 4;

  floatx4 acc[2][2];
#pragma unroll
  for (int i = 0; i < 2; ++i)
#pragma unroll
    for (int j = 0; j < 2; ++j) acc[i][j] = (floatx4){0.f, 0.f, 0.f, 0.f};

  const int lrow = tid >> 2;       // 0..63
  const int lcol = (tid & 3) * 8;  // 0,8,16,24
  const int br = tid >> 4;         // 0..15  (k-row for B staging)
  const int bc4 = (tid & 15) * 4;  // 0..60  (col group for B staging)

  for (int kt = 0; kt < N_EMBD; kt += BK) {
    // ---- A tile: fp32 -> bf16, [m][k] ----
    {
      const long base = (long)(bm + lrow) * N_EMBD + kt + lcol;
      const float4 f0 = *(const float4*)&X[base];
      const float4 f1 = *(const float4*)&X[base + 4];
      u16x8 p;
      p[0] = f2bf(f0.x); p[1] = f2bf(f0.y); p[2] = f2bf(f0.z); p[3] = f2bf(f0.w);
      p[4] = f2bf(f1.x); p[5] = f2bf(f1.y); p[6] = f2bf(f1.z); p[7] = f2bf(f1.w);
      *(u16x8*)&As[lrow * BK + lcol] = p;
    }
    // ---- B tile: transposing stage from row-major [K,3072] -> Bs[n][k] ----
#pragma unroll
    for (int p = 0; p < 2; ++p) {
      const int kr = br + p * 16;  // 0..31
      const float4 wv = *(const float4*)&W[(long)(kt + kr) * 3072 + bn + bc4];
      Bs[(bc4 + 0) * BK + kr] = f2bf(wv.x);
      Bs[(bc4 + 1) * BK + kr] = f2bf(wv.y);
      Bs[(bc4 + 2) * BK + kr] = f2bf(wv.z);
      Bs[(bc4 + 3) * BK + kr] = f2bf(wv.w);
    }
    __syncthreads();
    bf16x8 af[2], bfr[2];
#pragma unroll
    for (int i = 0; i < 2; ++i)
      af[i] = __builtin_bit_cast(
          bf16x8, *(const u16x8*)&As[(wm + i * 16 + m16) * BK + quad * 8]);
#pragma unroll
    for (int j = 0; j < 2; ++j)
      bfr[j] = __builtin_bit_cast(
          bf16x8, *(const u16x8*)&Bs[(wn + j * 16 + m16) * BK + quad * 8]);
#pragma unroll
    for (int i = 0; i < 2; ++i)
#pragma unroll
      for (int j = 0; j < 2; ++j)
        acc[i][j] = __builtin_amdgcn_mfma_f32_16x16x32_bf16(af[i], bfr[j],
                                                            acc[i][j], 0, 0, 0);
    __syncthreads();
  }

#pragma unroll
  for (int i = 0; i < 2; ++i) {
#pragma unroll
    for (int j = 0; j < 2; ++j) {
      const int col = bn + wn + j * 16 + m16;  // 0..3071
      const float bv = bias[col];
#pragma unroll
      for (int r = 0; r < 4; ++r) {
        const int row = bm + wm + i * 16 + quad * 4 + r;
        const u16 o = f2bf(acc[i][j][r] + bv);
        const int which = col >> 10;  // 0=q 1=k 2=v
        const int cc = col & 1023;
        const int h = cc >> 6;
        const int d = cc & 63;
        const int b = row >> 11;
        const int t = row & 2047;
        u16* dst = (which == 0) ? qo : ((which == 1) ? ko : vo);
        dst[(((long)(b * N_HEAD + h)) * SEQ + t) * HEAD_DIM + d] = o;
      }
    }
  }
}

// ==== attention: one block per (b,h,q-row); writes fp32 y into d_out ====
__global__ __launch_bounds__(256) void attn_kernel(const u16* __restrict__ Q,
                                                   const u16* __restrict__ K,
                                                   const u16* __restrict__ V,
                                                   float* __restrict__ Y) {
  const int qi = blockIdx.x;
  const int h = blockIdx.y;
  const int b = blockIdx.z;
  const int tid = threadIdx.x;
  const long bh = b * N_HEAD + h;

  __shared__ float qs[HEAD_DIM];
  __shared__ float sc[SEQ];
  __shared__ float red[256];

  const u16* qp = Q + (bh * SEQ + qi) * HEAD_DIM;
  if (tid < HEAD_DIM) qs[tid] = bf2f(qp[tid]);
  __syncthreads();

  const int nk = qi + 1;
  float lmax = -1e30f;
  for (int kk = tid; kk < nk; kk += 256) {
    const u16x8* kp = (const u16x8*)(K + (bh * SEQ + kk) * HEAD_DIM);
    float s = 0.f;
#pragma unroll
    for (int c = 0; c < 8; ++c) {
      u16x8 vv = kp[c];
#pragma unroll
      for (int j = 0; j < 8; ++j) s += qs[c * 8 + j] * bf2f(vv[j]);
    }
    s *= 0.125f;  // 1/sqrt(64)
    sc[kk] = s;
    lmax = fmaxf(lmax, s);
  }
  red[tid] = lmax;
  __syncthreads();
  for (int st = 128; st > 0; st >>= 1) {
    if (tid < st) red[tid] = fmaxf(red[tid], red[tid + st]);
    __syncthreads();
  }
  const float mx = red[0];
  __syncthreads();

  float lsum = 0.f;
  for (int kk = tid; kk < nk; kk += 256) {
    const float e = __expf(sc[kk] - mx);
    sc[kk] = e;
    lsum += e;
  }
  red[tid] = lsum;
  __syncthreads();
  for (int st = 128; st > 0; st >>= 1) {
    if (tid < st) red[tid] += red[tid + st];
    __syncthreads();
  }
  const float inv = 1.f / red[0];
  __syncthreads();

  const int w = tid >> 6;
  const int d = tid & 63;
  float acc = 0.f;
  for (int kk = w; kk < nk; kk += 4) {
    const u16* vp = V + (bh * SEQ + kk) * HEAD_DIM;
    acc += sc[kk] * bf2f(vp[d]);
  }
  red[tid] = acc;
  __syncthreads();
  if (tid < 64) {
    const float y = (red[d] + red[64 + d] + red[128 + d] + red[192 + d]) * inv;
    Y[((long)(b * SEQ + qi)) * N_EMBD + h * HEAD_DIM + d] = y;  // fp32
  }
}

// ======== proj GEMM, IN-PLACE on fp32 d_out ========
// Block owns 16 rows: stage y rows (fp32 -> bf16) to LDS, then out = y@Wp+b.
#define PM 16

__global__ __launch_bounds__(256) void proj_gemm(float* Y,  // aliased in+out
                                                 const float* __restrict__ W,
                                                 const float* __restrict__ bias) {
  __shared__ u16 ylds[PM * N_EMBD];  // 32 KB  [m][k] bf16
  __shared__ u16 Bs[256 * BK];       // 16 KB  [n_local][k] bf16
  const int tid = threadIdx.x;
  const int bm = blockIdx.x * PM;
  const int w = tid >> 6;
  const int l = tid & 63;
  const int m16 = l & 15;
  const int quad = l >> 4;

  // stage this block's 16 fp32 y-rows -> bf16 LDS
  for (int f = tid; f < PM * N_EMBD / 4; f += 256) {  // 4096 float4 groups
    const int row = f >> 8;          // 256 groups per row
    const int c4 = (f & 255) * 4;
    const float4 yv = *(const float4*)&Y[(long)(bm + row) * N_EMBD + c4];
    ylds[row * N_EMBD + c4 + 0] = f2bf(yv.x);
    ylds[row * N_EMBD + c4 + 1] = f2bf(yv.y);
    ylds[row * N_EMBD + c4 + 2] = f2bf(yv.z);
    ylds[row * N_EMBD + c4 + 3] = f2bf(yv.w);
  }
  __syncthreads();

  for (int bn = 0; bn < N_EMBD; bn += 256) {
    floatx4 acc[4];
#pragma unroll
    for (int j = 0; j < 4; ++j) acc[j] = (floatx4){0.f, 0.f, 0.f, 0.f};

    for (int kt = 0; kt < N_EMBD; kt += BK) {
      // stage Bs[c][k]: 32 k-rows x 256 cols from fp32 W[k][n]
#pragma unroll
      for (int p = 0; p < 8; ++p) {
        const int f = tid + 256 * p;
        const int kr = f >> 6;        // 0..31
        const int c4 = (f & 63) * 4;  // 0..252
        const float4 wv =
            *(const float4*)&W[(long)(kt + kr) * N_EMBD + bn + c4];
        Bs[(c4 + 0) * BK + kr] = f2bf(wv.x);
        Bs[(c4 + 1) * BK + kr] = f2bf(wv.y);
        Bs[(c4 + 2) * BK + kr] = f2bf(wv.z);
        Bs[(c4 + 3) * BK + kr] = f2bf(wv.w);
      }
      __syncthreads();
      const bf16x8 af = __builtin_bit_cast(
          bf16x8, *(const u16x8*)&ylds[m16 * N_EMBD + kt + quad * 8]);
#pragma unroll
      for (int j = 0; j < 4; ++j) {
        const bf16x8 bfr = __builtin_bit_cast(
            bf16x8,
            *(const u16x8*)&Bs[(w * 64 + j * 16 + m16) * BK + quad * 8]);
        acc[j] = __builtin_amdgcn_mfma_f32_16x16x32_bf16(af, bfr, acc[j], 0,
                                                         0, 0);
      }
      __syncthreads();
    }
    // epilogue for this 256-col slice (rows exclusively ours; y is in LDS)
#pragma unroll
    for (int j = 0; j < 4; ++j) {
      const int col = bn + w * 64 + j * 16 + m16;
      const float bv = bias[col];
#pragma unroll
      for (int r = 0; r < 4; ++r) {
        const int row = bm + quad * 4 + r;
        Y[(long)row * N_EMBD + col] = acc[j][r] + bv;  // fp32 out
      }
    }
  }
}

// ======== launch ========
extern "C" void kernel_launch(void* const* d_in, const int* in_sizes, int n_in,
                              void* d_out, int out_size, void* d_ws,
                              size_t ws_size, hipStream_t stream) {
  const float* x = (const float*)d_in[0];       // [B,T,C] fp32
  const float* w_attn = (const float*)d_in[1];  // [C, 3C] fp32
  const float* b_attn = (const float*)d_in[2];  // [3C]    fp32
  const float* w_proj = (const float*)d_in[3];  // [C, C]  fp32
  const float* b_proj = (const float*)d_in[4];  // [C]     fp32
  float* out = (float*)d_out;                   // [B,T,C] fp32

  // scratch: ONLY q/k/v, 3 x 8 MB = 24 MB
  char* ws = (char*)d_ws;
  const size_t SZ = (size_t)BATCH * N_HEAD * SEQ * HEAD_DIM * sizeof(u16);
  u16* q = (u16*)(ws);
  u16* k = (u16*)(ws + SZ);
  u16* v = (u16*)(ws + 2 * SZ);

  qkv_gemm<<<dim3(3 * N_EMBD / BN, M_ROWS / BM), 256, 0, stream>>>(
      x, w_attn, b_attn, q, k, v);

  attn_kernel<<<dim3(SEQ, N_HEAD, BATCH), 256, 0, stream>>>(q, k, v, out);

  proj_gemm<<<dim3(M_ROWS / PM), 256, 0, stream>>>(out, w_proj, b_proj);
}

// Round 5
// 985.923 us; speedup vs baseline: 3.2732x; 3.2732x over previous
//
#include <hip/hip_runtime.h>

typedef unsigned short u16;
typedef u16 u16x8 __attribute__((ext_vector_type(8)));
typedef __bf16 bf16x8 __attribute__((ext_vector_type(8)));
typedef float floatx4 __attribute__((ext_vector_type(4)));

#define N_EMBD 1024
#define N_HEAD 16
#define HEAD_DIM 64
#define SEQ 2048
#define BATCH 2
#define M_ROWS (BATCH * SEQ)  // 4096

__device__ __forceinline__ float bf2f(u16 b) {
  return __uint_as_float(((unsigned)b) << 16);
}
__device__ __forceinline__ u16 f2bf(float f) {
  unsigned u = __float_as_uint(f);
  u += 0x7fffu + ((u >> 16) & 1u);  // RNE
  return (u16)(u >> 16);
}

// ======== QKV GEMM: x_f32[M,1024] @ w_attn_f32[1024,3072] + b_attn ========
#define BM 64
#define BN 64
#define BK 32

__global__ __launch_bounds__(256) void qkv_gemm(const float* __restrict__ X,
                                                const float* __restrict__ W,
                                                const float* __restrict__ bias,
                                                u16* __restrict__ qo,
                                                u16* __restrict__ ko,
                                                u16* __restrict__ vo) {
  __shared__ u16 As[BM * BK];  // [m][k]
  __shared__ u16 Bs[BN * BK];  // [n][k]
  const int tid = threadIdx.x;
  const int bm = blockIdx.y * BM;
  const int bn = blockIdx.x * BN;
  const int w = tid >> 6;
  const int l = tid & 63;
  const int wm = (w >> 1) * 32;
  const int wn = (w & 1) * 32;
  const int m16 = l & 15;
  const int quad = l >> 4;

  floatx4 acc[2][2];
#pragma unroll
  for (int i = 0; i < 2; ++i)
#pragma unroll
    for (int j = 0; j < 2; ++j) acc[i][j] = (floatx4){0.f, 0.f, 0.f, 0.f};

  const int lrow = tid >> 2;
  const int lcol = (tid & 3) * 8;
  const int br = tid >> 4;
  const int bc4 = (tid & 15) * 4;

  for (int kt = 0; kt < N_EMBD; kt += BK) {
    {
      const long base = (long)(bm + lrow) * N_EMBD + kt + lcol;
      const float4 f0 = *(const float4*)&X[base];
      const float4 f1 = *(const float4*)&X[base + 4];
      u16x8 p;
      p[0] = f2bf(f0.x); p[1] = f2bf(f0.y); p[2] = f2bf(f0.z); p[3] = f2bf(f0.w);
      p[4] = f2bf(f1.x); p[5] = f2bf(f1.y); p[6] = f2bf(f1.z); p[7] = f2bf(f1.w);
      *(u16x8*)&As[lrow * BK + lcol] = p;
    }
#pragma unroll
    for (int p = 0; p < 2; ++p) {
      const int kr = br + p * 16;
      const float4 wv = *(const float4*)&W[(long)(kt + kr) * 3072 + bn + bc4];
      Bs[(bc4 + 0) * BK + kr] = f2bf(wv.x);
      Bs[(bc4 + 1) * BK + kr] = f2bf(wv.y);
      Bs[(bc4 + 2) * BK + kr] = f2bf(wv.z);
      Bs[(bc4 + 3) * BK + kr] = f2bf(wv.w);
    }
    __syncthreads();
    bf16x8 af[2], bfr[2];
#pragma unroll
    for (int i = 0; i < 2; ++i)
      af[i] = __builtin_bit_cast(
          bf16x8, *(const u16x8*)&As[(wm + i * 16 + m16) * BK + quad * 8]);
#pragma unroll
    for (int j = 0; j < 2; ++j)
      bfr[j] = __builtin_bit_cast(
          bf16x8, *(const u16x8*)&Bs[(wn + j * 16 + m16) * BK + quad * 8]);
#pragma unroll
    for (int i = 0; i < 2; ++i)
#pragma unroll
      for (int j = 0; j < 2; ++j)
        acc[i][j] = __builtin_amdgcn_mfma_f32_16x16x32_bf16(af[i], bfr[j],
                                                            acc[i][j], 0, 0, 0);
    __syncthreads();
  }

#pragma unroll
  for (int i = 0; i < 2; ++i) {
#pragma unroll
    for (int j = 0; j < 2; ++j) {
      const int col = bn + wn + j * 16 + m16;
      const float bv = bias[col];
#pragma unroll
      for (int r = 0; r < 4; ++r) {
        const int row = bm + wm + i * 16 + quad * 4 + r;
        const u16 o = f2bf(acc[i][j][r] + bv);
        const int which = col >> 10;  // 0=q 1=k 2=v
        const int cc = col & 1023;
        const int h = cc >> 6;
        const int d = cc & 63;
        const int b = row >> 11;
        const int t = row & 2047;
        u16* dst = (which == 0) ? qo : ((which == 1) ? ko : vo);
        dst[(((long)(b * N_HEAD + h)) * SEQ + t) * HEAD_DIM + d] = o;
      }
    }
  }
}

// ======== flash attention (MFMA, online softmax) ========
// block = 4 waves; wave w owns q rows [qb+16w, qb+16w+16); KV tiles of 64.
#define BQ 64
#define BKV 64
#define KPAD 72  // LDS row stride (u16) — m97-class conflict-free b128 reads
#define LOG2E 1.44269504f

__global__ __launch_bounds__(256) void flash_attn(const u16* __restrict__ Q,
                                                  const u16* __restrict__ K,
                                                  const u16* __restrict__ V,
                                                  float* __restrict__ Y) {
  const int iq = blockIdx.x;
  const int h = blockIdx.y;
  const int b = blockIdx.z;
  const long bh = b * N_HEAD + h;
  const int tid = threadIdx.x;
  const int w = tid >> 6;
  const int l = tid & 63;
  const int m16 = l & 15;
  const int quad = l >> 4;
  const int qb = iq * BQ;

  __shared__ u16 Kl[BKV * KPAD];       // [key][d]
  __shared__ u16 Vl[HEAD_DIM * KPAD];  // [d][key]  (transposed)
  __shared__ u16 Pl[4][16 * KPAD];     // per-wave [q][key]

  // Q fragments (A-layout): rows qb+16w+m16, k = kk*32 + quad*8 + j
  bf16x8 qf[2];
  {
    const u16* qrow = Q + (bh * SEQ + qb + w * 16 + m16) * HEAD_DIM;
    qf[0] = __builtin_bit_cast(bf16x8, *(const u16x8*)&qrow[quad * 8]);
    qf[1] = __builtin_bit_cast(bf16x8, *(const u16x8*)&qrow[32 + quad * 8]);
  }

  floatx4 Oacc[4];
#pragma unroll
  for (int t = 0; t < 4; ++t) Oacc[t] = (floatx4){0.f, 0.f, 0.f, 0.f};
  float mrow[4] = {-1e30f, -1e30f, -1e30f, -1e30f};
  float lrow[4] = {0.f, 0.f, 0.f, 0.f};

  const int ntiles = iq + 1;
  for (int it = 0; it < ntiles; ++it) {
    const int kt = it * BKV;
    // ---- stage K [key][d] ----
#pragma unroll
    for (int i = 0; i < 2; ++i) {
      const int p = tid + 256 * i;
      const int key = p >> 3, dg = p & 7;
      *(u16x8*)&Kl[key * KPAD + dg * 8] =
          *(const u16x8*)&K[(bh * SEQ + kt + key) * HEAD_DIM + dg * 8];
    }
    // ---- stage V transposed -> [d][key] ----
#pragma unroll
    for (int i = 0; i < 2; ++i) {
      const int p = tid + 256 * i;
      const int key = p & 63, dg = p >> 6;  // dg 0..7 over the 2 iters
      const u16x8 vv =
          *(const u16x8*)&V[(bh * SEQ + kt + key) * HEAD_DIM + dg * 8];
#pragma unroll
      for (int j = 0; j < 8; ++j) Vl[(dg * 8 + j) * KPAD + key] = vv[j];
    }
    __syncthreads();

    // ---- S = Q K^T : 4 key-ntiles x 2 ksteps ----
    floatx4 s[4];
#pragma unroll
    for (int j = 0; j < 4; ++j) s[j] = (floatx4){0.f, 0.f, 0.f, 0.f};
#pragma unroll
    for (int j = 0; j < 4; ++j)
#pragma unroll
      for (int kk = 0; kk < 2; ++kk) {
        const bf16x8 kf = __builtin_bit_cast(
            bf16x8,
            *(const u16x8*)&Kl[(j * 16 + m16) * KPAD + kk * 32 + quad * 8]);
        s[j] = __builtin_amdgcn_mfma_f32_16x16x32_bf16(qf[kk], kf, s[j], 0, 0,
                                                       0);
      }
    // scale, then causal mask on the diagonal tile
#pragma unroll
    for (int j = 0; j < 4; ++j)
#pragma unroll
      for (int r = 0; r < 4; ++r) s[j][r] *= 0.125f;
    if (it == ntiles - 1) {
      const int qg = qb + w * 16 + quad * 4;  // + r
#pragma unroll
      for (int j = 0; j < 4; ++j) {
        const int keyg = kt + j * 16 + m16;
#pragma unroll
        for (int r = 0; r < 4; ++r)
          if (keyg > qg + r) s[j][r] = -1e30f;
      }
    }

    // ---- online softmax ----
    float tm[4];
#pragma unroll
    for (int r = 0; r < 4; ++r)
      tm[r] = fmaxf(fmaxf(s[0][r], s[1][r]), fmaxf(s[2][r], s[3][r]));
#pragma unroll
    for (int d = 1; d < 16; d <<= 1)
#pragma unroll
      for (int r = 0; r < 4; ++r)
        tm[r] = fmaxf(tm[r], __shfl_xor(tm[r], d, 64));
    float mn[4], al[4];
#pragma unroll
    for (int r = 0; r < 4; ++r) {
      mn[r] = fmaxf(mrow[r], tm[r]);
      al[r] = exp2f((mrow[r] - mn[r]) * LOG2E);
      mrow[r] = mn[r];
    }
    float ls[4] = {0.f, 0.f, 0.f, 0.f};
#pragma unroll
    for (int j = 0; j < 4; ++j) {
#pragma unroll
      for (int r = 0; r < 4; ++r) {
        const float p = exp2f((s[j][r] - mn[r]) * LOG2E);
        ls[r] += p;
        Pl[w][(quad * 4 + r) * KPAD + j * 16 + m16] = f2bf(p);
      }
    }
#pragma unroll
    for (int d = 1; d < 16; d <<= 1)
#pragma unroll
      for (int r = 0; r < 4; ++r) ls[r] += __shfl_xor(ls[r], d, 64);
#pragma unroll
    for (int r = 0; r < 4; ++r) lrow[r] = lrow[r] * al[r] + ls[r];
#pragma unroll
    for (int t = 0; t < 4; ++t)
#pragma unroll
      for (int r = 0; r < 4; ++r) Oacc[t][r] *= al[r];

    // ---- O += P V  (P via per-wave LDS round-trip; wave-local, no barrier)
    bf16x8 pf[2];
    pf[0] = __builtin_bit_cast(bf16x8,
                               *(const u16x8*)&Pl[w][m16 * KPAD + quad * 8]);
    pf[1] = __builtin_bit_cast(
        bf16x8, *(const u16x8*)&Pl[w][m16 * KPAD + 32 + quad * 8]);
#pragma unroll
    for (int t = 0; t < 4; ++t)
#pragma unroll
      for (int kk = 0; kk < 2; ++kk) {
        const bf16x8 vf = __builtin_bit_cast(
            bf16x8,
            *(const u16x8*)&Vl[(t * 16 + m16) * KPAD + kk * 32 + quad * 8]);
        Oacc[t] = __builtin_amdgcn_mfma_f32_16x16x32_bf16(pf[kk], vf, Oacc[t],
                                                          0, 0, 0);
      }
    __syncthreads();
  }

  // ---- epilogue: normalize, write fp32 y into d_out [B,T,C] ----
  float inv[4];
#pragma unroll
  for (int r = 0; r < 4; ++r) inv[r] = 1.f / lrow[r];
#pragma unroll
  for (int t = 0; t < 4; ++t)
#pragma unroll
    for (int r = 0; r < 4; ++r) {
      const int row = qb + w * 16 + quad * 4 + r;
      Y[((long)(b * SEQ + row)) * N_EMBD + h * HEAD_DIM + t * 16 + m16] =
          Oacc[t][r] * inv[r];
    }
}

// ======== proj GEMM, IN-PLACE on fp32 d_out ========
#define PM 16

__global__ __launch_bounds__(256) void proj_gemm(float* Y,  // aliased in+out
                                                 const float* __restrict__ W,
                                                 const float* __restrict__ bias) {
  __shared__ u16 ylds[PM * N_EMBD];  // [m][k] bf16
  __shared__ u16 Bs[256 * BK];       // [n_local][k] bf16
  const int tid = threadIdx.x;
  const int bm = blockIdx.x * PM;
  const int w = tid >> 6;
  const int l = tid & 63;
  const int m16 = l & 15;
  const int quad = l >> 4;

  for (int f = tid; f < PM * N_EMBD / 4; f += 256) {
    const int row = f >> 8;
    const int c4 = (f & 255) * 4;
    const float4 yv = *(const float4*)&Y[(long)(bm + row) * N_EMBD + c4];
    ylds[row * N_EMBD + c4 + 0] = f2bf(yv.x);
    ylds[row * N_EMBD + c4 + 1] = f2bf(yv.y);
    ylds[row * N_EMBD + c4 + 2] = f2bf(yv.z);
    ylds[row * N_EMBD + c4 + 3] = f2bf(yv.w);
  }
  __syncthreads();

  for (int bn = 0; bn < N_EMBD; bn += 256) {
    floatx4 acc[4];
#pragma unroll
    for (int j = 0; j < 4; ++j) acc[j] = (floatx4){0.f, 0.f, 0.f, 0.f};

    for (int kt = 0; kt < N_EMBD; kt += BK) {
#pragma unroll
      for (int p = 0; p < 8; ++p) {
        const int f = tid + 256 * p;
        const int kr = f >> 6;
        const int c4 = (f & 63) * 4;
        const float4 wv =
            *(const float4*)&W[(long)(kt + kr) * N_EMBD + bn + c4];
        Bs[(c4 + 0) * BK + kr] = f2bf(wv.x);
        Bs[(c4 + 1) * BK + kr] = f2bf(wv.y);
        Bs[(c4 + 2) * BK + kr] = f2bf(wv.z);
        Bs[(c4 + 3) * BK + kr] = f2bf(wv.w);
      }
      __syncthreads();
      const bf16x8 af = __builtin_bit_cast(
          bf16x8, *(const u16x8*)&ylds[m16 * N_EMBD + kt + quad * 8]);
#pragma unroll
      for (int j = 0; j < 4; ++j) {
        const bf16x8 bfr = __builtin_bit_cast(
            bf16x8,
            *(const u16x8*)&Bs[(w * 64 + j * 16 + m16) * BK + quad * 8]);
        acc[j] = __builtin_amdgcn_mfma_f32_16x16x32_bf16(af, bfr, acc[j], 0,
                                                         0, 0);
      }
      __syncthreads();
    }
#pragma unroll
    for (int j = 0; j < 4; ++j) {
      const int col = bn + w * 64 + j * 16 + m16;
      const float bv = bias[col];
#pragma unroll
      for (int r = 0; r < 4; ++r) {
        const int row = bm + quad * 4 + r;
        Y[(long)row * N_EMBD + col] = acc[j][r] + bv;
      }
    }
  }
}

// ======== launch ========
extern "C" void kernel_launch(void* const* d_in, const int* in_sizes, int n_in,
                              void* d_out, int out_size, void* d_ws,
                              size_t ws_size, hipStream_t stream) {
  const float* x = (const float*)d_in[0];
  const float* w_attn = (const float*)d_in[1];
  const float* b_attn = (const float*)d_in[2];
  const float* w_proj = (const float*)d_in[3];
  const float* b_proj = (const float*)d_in[4];
  float* out = (float*)d_out;

  char* ws = (char*)d_ws;
  const size_t SZ = (size_t)BATCH * N_HEAD * SEQ * HEAD_DIM * sizeof(u16);
  u16* q = (u16*)(ws);
  u16* k = (u16*)(ws + SZ);
  u16* v = (u16*)(ws + 2 * SZ);

  qkv_gemm<<<dim3(3 * N_EMBD / BN, M_ROWS / BM), 256, 0, stream>>>(
      x, w_attn, b_attn, q, k, v);

  flash_attn<<<dim3(SEQ / BQ, N_HEAD, BATCH), 256, 0, stream>>>(q, k, v, out);

  proj_gemm<<<dim3(M_ROWS / PM), 256, 0, stream>>>(out, w_proj, b_proj);
}

// Round 6
// 354.039 us; speedup vs baseline: 9.1151x; 2.7848x over previous
//
#include <hip/hip_runtime.h>

typedef unsigned short u16;
typedef u16 u16x8 __attribute__((ext_vector_type(8)));
typedef __bf16 bf16x8 __attribute__((ext_vector_type(8)));
typedef float floatx4 __attribute__((ext_vector_type(4)));

#define N_EMBD 1024
#define N_HEAD 16
#define HEAD_DIM 64
#define SEQ 2048
#define BATCH 2
#define M_ROWS (BATCH * SEQ)  // 4096

__device__ __forceinline__ float bf2f(u16 b) {
  return __uint_as_float(((unsigned)b) << 16);
}
__device__ __forceinline__ u16 f2bf(float f) {
  unsigned u = __float_as_uint(f);
  u += 0x7fffu + ((u >> 16) & 1u);  // RNE
  return (u16)(u >> 16);
}

// ======== transpose+convert: out_bf16[C][R] = in_f32[R][C] ========
__global__ __launch_bounds__(256) void transpose_k(const float* __restrict__ in,
                                                   u16* __restrict__ out,
                                                   int R, int C) {
  __shared__ u16 tile[32][33];
  int bx = blockIdx.x * 32;  // col base
  int by = blockIdx.y * 32;  // row base
  int tx = threadIdx.x;      // 0..31
  int ty = threadIdx.y;      // 0..7
#pragma unroll
  for (int j = 0; j < 32; j += 8)
    tile[ty + j][tx] = f2bf(in[(long)(by + ty + j) * C + bx + tx]);
  __syncthreads();
#pragma unroll
  for (int j = 0; j < 32; j += 8)
    out[(long)(bx + ty + j) * R + by + tx] = tile[tx][ty + j];
}

// ======== 128x128 GEMM vs pre-transposed bf16 B^T [N][K] ========
// MODE 0: A = fp32 X[M,K], epilogue scatters bf16 into q/k/v [B,H,T,D]
// MODE 1: A = bf16 q-buffer ([B,H,T,D] remap), epilogue writes fp32 out+bias
#define BK 32

template <int MODE>
__global__ __launch_bounds__(256) void gemm128(
    const void* __restrict__ Asrc, const u16* __restrict__ Bt,
    const float* __restrict__ bias, float* __restrict__ out,
    u16* __restrict__ qo, u16* __restrict__ ko, u16* __restrict__ vo, int N,
    int K) {
  __shared__ u16 As[128 * BK];
  __shared__ u16 Bs[128 * BK];
  const int tid = threadIdx.x;
  const int bm = blockIdx.y * 128;
  const int bn = blockIdx.x * 128;
  const int w = tid >> 6;
  const int l = tid & 63;
  const int wm = (w >> 1) * 64;
  const int wn = (w & 1) * 64;
  const int m16 = l & 15;
  const int quad = l >> 4;
  const int srow = tid >> 2;       // 0..63
  const int scol = (tid & 3) * 8;  // 0,8,16,24

  floatx4 acc[4][4];
#pragma unroll
  for (int i = 0; i < 4; ++i)
#pragma unroll
    for (int j = 0; j < 4; ++j) acc[i][j] = (floatx4){0.f, 0.f, 0.f, 0.f};

  for (int kt = 0; kt < K; kt += BK) {
#pragma unroll
    for (int p = 0; p < 2; ++p) {
      const int row = p * 64 + srow;
      // ---- A tile (contiguous u16x8 store, conflict-free) ----
      u16x8 d;
      if (MODE == 0) {
        const float* X = (const float*)Asrc;
        const long base = (long)(bm + row) * K + kt + scol;
        const float4 f0 = *(const float4*)&X[base];
        const float4 f1 = *(const float4*)&X[base + 4];
        d[0] = f2bf(f0.x); d[1] = f2bf(f0.y); d[2] = f2bf(f0.z); d[3] = f2bf(f0.w);
        d[4] = f2bf(f1.x); d[5] = f2bf(f1.y); d[6] = f2bf(f1.z); d[7] = f2bf(f1.w);
      } else {
        const u16* qb = (const u16*)Asrc;
        const int m = bm + row;
        const int b = m >> 11, t = m & 2047;
        const int k0 = kt + scol;
        const int head = k0 >> 6, dd = k0 & 63;  // BK=32 never crosses a head
        d = *(const u16x8*)&qb[(((long)(b * N_HEAD + head)) * SEQ + t) *
                                   HEAD_DIM +
                               dd];
      }
      *(u16x8*)&As[row * BK + scol] = d;
      // ---- B tile (bf16 direct copy) ----
      *(u16x8*)&Bs[row * BK + scol] =
          *(const u16x8*)&Bt[(long)(bn + row) * K + kt + scol];
    }
    __syncthreads();
    bf16x8 af[4], bfr[4];
#pragma unroll
    for (int i = 0; i < 4; ++i)
      af[i] = __builtin_bit_cast(
          bf16x8, *(const u16x8*)&As[(wm + i * 16 + m16) * BK + quad * 8]);
#pragma unroll
    for (int j = 0; j < 4; ++j)
      bfr[j] = __builtin_bit_cast(
          bf16x8, *(const u16x8*)&Bs[(wn + j * 16 + m16) * BK + quad * 8]);
#pragma unroll
    for (int i = 0; i < 4; ++i)
#pragma unroll
      for (int j = 0; j < 4; ++j)
        acc[i][j] = __builtin_amdgcn_mfma_f32_16x16x32_bf16(af[i], bfr[j],
                                                            acc[i][j], 0, 0, 0);
    __syncthreads();
  }

#pragma unroll
  for (int i = 0; i < 4; ++i) {
#pragma unroll
    for (int j = 0; j < 4; ++j) {
      const int col = bn + wn + j * 16 + m16;
      const float bv = bias[col];
#pragma unroll
      for (int r = 0; r < 4; ++r) {
        const int row = bm + wm + i * 16 + quad * 4 + r;
        const float v = acc[i][j][r] + bv;
        if (MODE == 1) {
          out[(long)row * N_EMBD + col] = v;
        } else {
          const u16 o = f2bf(v);
          const int which = col >> 10;  // 0=q 1=k 2=v
          const int cc = col & 1023;
          const int h = cc >> 6;
          const int dd = cc & 63;
          const int b = row >> 11;
          const int t = row & 2047;
          u16* dst = (which == 0) ? qo : ((which == 1) ? ko : vo);
          dst[(((long)(b * N_HEAD + h)) * SEQ + t) * HEAD_DIM + dd] = o;
        }
      }
    }
  }
}

// ======== flash attention (MFMA, online softmax) ========
// block = 4 waves; wave w owns q rows [qb+16w, qb+16w+16); KV tiles of 64.
// Writes bf16 y IN-PLACE into the q buffer (each block reads only its own
// Q tile, once, before the loop — no cross-block Q reuse).
#define BQ 64
#define BKV 64
#define KPAD 72
#define LOG2E 1.44269504f

__global__ __launch_bounds__(256) void flash_attn(u16* __restrict__ Qy,
                                                  const u16* __restrict__ K,
                                                  const u16* __restrict__ V) {
  const int iq = blockIdx.x;
  const int h = blockIdx.y;
  const int b = blockIdx.z;
  const long bh = b * N_HEAD + h;
  const int tid = threadIdx.x;
  const int w = tid >> 6;
  const int l = tid & 63;
  const int m16 = l & 15;
  const int quad = l >> 4;
  const int qb = iq * BQ;

  __shared__ u16 Kl[BKV * KPAD];       // [key][d]
  __shared__ u16 Vl[HEAD_DIM * KPAD];  // [d][key]  (transposed)
  __shared__ u16 Pl[4][16 * KPAD];     // per-wave [q][key]

  bf16x8 qf[2];
  {
    const u16* qrow = Qy + (bh * SEQ + qb + w * 16 + m16) * HEAD_DIM;
    qf[0] = __builtin_bit_cast(bf16x8, *(const u16x8*)&qrow[quad * 8]);
    qf[1] = __builtin_bit_cast(bf16x8, *(const u16x8*)&qrow[32 + quad * 8]);
  }

  floatx4 Oacc[4];
#pragma unroll
  for (int t = 0; t < 4; ++t) Oacc[t] = (floatx4){0.f, 0.f, 0.f, 0.f};
  float mrow[4] = {-1e30f, -1e30f, -1e30f, -1e30f};
  float lrow[4] = {0.f, 0.f, 0.f, 0.f};

  const int ntiles = iq + 1;
  for (int it = 0; it < ntiles; ++it) {
    const int kt = it * BKV;
#pragma unroll
    for (int i = 0; i < 2; ++i) {
      const int p = tid + 256 * i;
      const int key = p >> 3, dg = p & 7;
      *(u16x8*)&Kl[key * KPAD + dg * 8] =
          *(const u16x8*)&K[(bh * SEQ + kt + key) * HEAD_DIM + dg * 8];
    }
#pragma unroll
    for (int i = 0; i < 2; ++i) {
      const int p = tid + 256 * i;
      const int key = p & 63, dg = p >> 6;
      const u16x8 vv =
          *(const u16x8*)&V[(bh * SEQ + kt + key) * HEAD_DIM + dg * 8];
#pragma unroll
      for (int j = 0; j < 8; ++j) Vl[(dg * 8 + j) * KPAD + key] = vv[j];
    }
    __syncthreads();

    floatx4 s[4];
#pragma unroll
    for (int j = 0; j < 4; ++j) s[j] = (floatx4){0.f, 0.f, 0.f, 0.f};
#pragma unroll
    for (int j = 0; j < 4; ++j)
#pragma unroll
      for (int kk = 0; kk < 2; ++kk) {
        const bf16x8 kf = __builtin_bit_cast(
            bf16x8,
            *(const u16x8*)&Kl[(j * 16 + m16) * KPAD + kk * 32 + quad * 8]);
        s[j] = __builtin_amdgcn_mfma_f32_16x16x32_bf16(qf[kk], kf, s[j], 0, 0,
                                                       0);
      }
#pragma unroll
    for (int j = 0; j < 4; ++j)
#pragma unroll
      for (int r = 0; r < 4; ++r) s[j][r] *= 0.125f;
    if (it == ntiles - 1) {
      const int qg = qb + w * 16 + quad * 4;
#pragma unroll
      for (int j = 0; j < 4; ++j) {
        const int keyg = kt + j * 16 + m16;
#pragma unroll
        for (int r = 0; r < 4; ++r)
          if (keyg > qg + r) s[j][r] = -1e30f;
      }
    }

    float tm[4];
#pragma unroll
    for (int r = 0; r < 4; ++r)
      tm[r] = fmaxf(fmaxf(s[0][r], s[1][r]), fmaxf(s[2][r], s[3][r]));
#pragma unroll
    for (int d = 1; d < 16; d <<= 1)
#pragma unroll
      for (int r = 0; r < 4; ++r)
        tm[r] = fmaxf(tm[r], __shfl_xor(tm[r], d, 64));
    float mn[4], al[4];
#pragma unroll
    for (int r = 0; r < 4; ++r) {
      mn[r] = fmaxf(mrow[r], tm[r]);
      al[r] = exp2f((mrow[r] - mn[r]) * LOG2E);
      mrow[r] = mn[r];
    }
    float ls[4] = {0.f, 0.f, 0.f, 0.f};
#pragma unroll
    for (int j = 0; j < 4; ++j) {
#pragma unroll
      for (int r = 0; r < 4; ++r) {
        const float p = exp2f((s[j][r] - mn[r]) * LOG2E);
        ls[r] += p;
        Pl[w][(quad * 4 + r) * KPAD + j * 16 + m16] = f2bf(p);
      }
    }
#pragma unroll
    for (int d = 1; d < 16; d <<= 1)
#pragma unroll
      for (int r = 0; r < 4; ++r) ls[r] += __shfl_xor(ls[r], d, 64);
#pragma unroll
    for (int r = 0; r < 4; ++r) lrow[r] = lrow[r] * al[r] + ls[r];
#pragma unroll
    for (int t = 0; t < 4; ++t)
#pragma unroll
      for (int r = 0; r < 4; ++r) Oacc[t][r] *= al[r];

    bf16x8 pf[2];
    pf[0] = __builtin_bit_cast(bf16x8,
                               *(const u16x8*)&Pl[w][m16 * KPAD + quad * 8]);
    pf[1] = __builtin_bit_cast(
        bf16x8, *(const u16x8*)&Pl[w][m16 * KPAD + 32 + quad * 8]);
#pragma unroll
    for (int t = 0; t < 4; ++t)
#pragma unroll
      for (int kk = 0; kk < 2; ++kk) {
        const bf16x8 vf = __builtin_bit_cast(
            bf16x8,
            *(const u16x8*)&Vl[(t * 16 + m16) * KPAD + kk * 32 + quad * 8]);
        Oacc[t] = __builtin_amdgcn_mfma_f32_16x16x32_bf16(pf[kk], vf, Oacc[t],
                                                          0, 0, 0);
      }
    __syncthreads();
  }

  // epilogue: normalize, write bf16 y back into the q buffer (same layout)
  float inv[4];
#pragma unroll
  for (int r = 0; r < 4; ++r) inv[r] = 1.f / lrow[r];
#pragma unroll
  for (int t = 0; t < 4; ++t)
#pragma unroll
    for (int r = 0; r < 4; ++r) {
      const int row = qb + w * 16 + quad * 4 + r;
      Qy[(bh * SEQ + row) * HEAD_DIM + t * 16 + m16] =
          f2bf(Oacc[t][r] * inv[r]);
    }
}

// ======== launch ========
extern "C" void kernel_launch(void* const* d_in, const int* in_sizes, int n_in,
                              void* d_out, int out_size, void* d_ws,
                              size_t ws_size, hipStream_t stream) {
  const float* x = (const float*)d_in[0];
  const float* w_attn = (const float*)d_in[1];
  const float* b_attn = (const float*)d_in[2];
  const float* w_proj = (const float*)d_in[3];
  const float* b_proj = (const float*)d_in[4];
  float* out = (float*)d_out;

  // ws: q 8MB | k 8MB | v 8MB | wT_a 6MB | wT_p 2MB  = 32 MB
  char* ws = (char*)d_ws;
  const size_t SZ = (size_t)BATCH * N_HEAD * SEQ * HEAD_DIM * sizeof(u16);
  u16* q = (u16*)(ws);
  u16* k = (u16*)(ws + SZ);
  u16* v = (u16*)(ws + 2 * SZ);
  u16* wT_a = (u16*)(ws + 3 * SZ);
  u16* wT_p = (u16*)(ws + 3 * SZ + (size_t)3 * N_EMBD * N_EMBD * sizeof(u16));

  transpose_k<<<dim3(3 * N_EMBD / 32, N_EMBD / 32), dim3(32, 8), 0, stream>>>(
      w_attn, wT_a, N_EMBD, 3 * N_EMBD);
  transpose_k<<<dim3(N_EMBD / 32, N_EMBD / 32), dim3(32, 8), 0, stream>>>(
      w_proj, wT_p, N_EMBD, N_EMBD);

  gemm128<0><<<dim3(3 * N_EMBD / 128, M_ROWS / 128), 256, 0, stream>>>(
      x, wT_a, b_attn, nullptr, q, k, v, 3 * N_EMBD, N_EMBD);

  flash_attn<<<dim3(SEQ / BQ, N_HEAD, BATCH), 256, 0, stream>>>(q, k, v);

  gemm128<1><<<dim3(N_EMBD / 128, M_ROWS / 128), 256, 0, stream>>>(
      q, wT_p, b_proj, out, nullptr, nullptr, nullptr, N_EMBD, N_EMBD);
}

// Round 7
// 255.377 us; speedup vs baseline: 12.6366x; 1.3863x over previous
//
#include <hip/hip_runtime.h>

typedef unsigned short u16;
typedef u16 u16x8 __attribute__((ext_vector_type(8)));
typedef __bf16 bf16x8 __attribute__((ext_vector_type(8)));
typedef float floatx4 __attribute__((ext_vector_type(4)));

#define N_EMBD 1024
#define N_HEAD 16
#define HEAD_DIM 64
#define SEQ 2048
#define BATCH 2
#define M_ROWS (BATCH * SEQ)  // 4096

__device__ __forceinline__ float bf2f(u16 b) {
  return __uint_as_float(((unsigned)b) << 16);
}
__device__ __forceinline__ u16 f2bf(float f) {
  unsigned u = __float_as_uint(f);
  u += 0x7fffu + ((u >> 16) & 1u);  // RNE
  return (u16)(u >> 16);
}

// ======== transpose+convert: out_bf16[C][R] = in_f32[R][C] ========
__global__ __launch_bounds__(256) void transpose_k(const float* __restrict__ in,
                                                   u16* __restrict__ out,
                                                   int R, int C) {
  __shared__ u16 tile[32][33];
  int bx = blockIdx.x * 32;
  int by = blockIdx.y * 32;
  int tx = threadIdx.x;
  int ty = threadIdx.y;
#pragma unroll
  for (int j = 0; j < 32; j += 8)
    tile[ty + j][tx] = f2bf(in[(long)(by + ty + j) * C + bx + tx]);
  __syncthreads();
#pragma unroll
  for (int j = 0; j < 32; j += 8)
    out[(long)(bx + ty + j) * R + by + tx] = tile[tx][ty + j];
}

// ======== 128x128 GEMM vs pre-transposed bf16 B^T [N][K] ========
// MODE 0: A = fp32 X[M,K], epilogue scatters bf16 into q/k/v [B,H,T,D]
// MODE 1: A = bf16 q-buffer ([B,H,T,D] remap), epilogue writes fp32 out+bias
#define BK 32

template <int MODE>
__global__ __launch_bounds__(256) void gemm128(
    const void* __restrict__ Asrc, const u16* __restrict__ Bt,
    const float* __restrict__ bias, float* __restrict__ out,
    u16* __restrict__ qo, u16* __restrict__ ko, u16* __restrict__ vo, int N,
    int K) {
  __shared__ u16 As[128 * BK];
  __shared__ u16 Bs[128 * BK];
  const int tid = threadIdx.x;
  const int bm = blockIdx.y * 128;
  const int bn = blockIdx.x * 128;
  const int w = tid >> 6;
  const int l = tid & 63;
  const int wm = (w >> 1) * 64;
  const int wn = (w & 1) * 64;
  const int m16 = l & 15;
  const int quad = l >> 4;
  const int srow = tid >> 2;
  const int scol = (tid & 3) * 8;

  floatx4 acc[4][4];
#pragma unroll
  for (int i = 0; i < 4; ++i)
#pragma unroll
    for (int j = 0; j < 4; ++j) acc[i][j] = (floatx4){0.f, 0.f, 0.f, 0.f};

  for (int kt = 0; kt < K; kt += BK) {
#pragma unroll
    for (int p = 0; p < 2; ++p) {
      const int row = p * 64 + srow;
      u16x8 d;
      if (MODE == 0) {
        const float* X = (const float*)Asrc;
        const long base = (long)(bm + row) * K + kt + scol;
        const float4 f0 = *(const float4*)&X[base];
        const float4 f1 = *(const float4*)&X[base + 4];
        d[0] = f2bf(f0.x); d[1] = f2bf(f0.y); d[2] = f2bf(f0.z); d[3] = f2bf(f0.w);
        d[4] = f2bf(f1.x); d[5] = f2bf(f1.y); d[6] = f2bf(f1.z); d[7] = f2bf(f1.w);
      } else {
        const u16* qb = (const u16*)Asrc;
        const int m = bm + row;
        const int b = m >> 11, t = m & 2047;
        const int k0 = kt + scol;
        const int head = k0 >> 6, dd = k0 & 63;
        d = *(const u16x8*)&qb[(((long)(b * N_HEAD + head)) * SEQ + t) *
                                   HEAD_DIM +
                               dd];
      }
      *(u16x8*)&As[row * BK + scol] = d;
      *(u16x8*)&Bs[row * BK + scol] =
          *(const u16x8*)&Bt[(long)(bn + row) * K + kt + scol];
    }
    __syncthreads();
    bf16x8 af[4], bfr[4];
#pragma unroll
    for (int i = 0; i < 4; ++i)
      af[i] = __builtin_bit_cast(
          bf16x8, *(const u16x8*)&As[(wm + i * 16 + m16) * BK + quad * 8]);
#pragma unroll
    for (int j = 0; j < 4; ++j)
      bfr[j] = __builtin_bit_cast(
          bf16x8, *(const u16x8*)&Bs[(wn + j * 16 + m16) * BK + quad * 8]);
#pragma unroll
    for (int i = 0; i < 4; ++i)
#pragma unroll
      for (int j = 0; j < 4; ++j)
        acc[i][j] = __builtin_amdgcn_mfma_f32_16x16x32_bf16(af[i], bfr[j],
                                                            acc[i][j], 0, 0, 0);
    __syncthreads();
  }

#pragma unroll
  for (int i = 0; i < 4; ++i) {
#pragma unroll
    for (int j = 0; j < 4; ++j) {
      const int col = bn + wn + j * 16 + m16;
      const float bv = bias[col];
#pragma unroll
      for (int r = 0; r < 4; ++r) {
        const int row = bm + wm + i * 16 + quad * 4 + r;
        const float v = acc[i][j][r] + bv;
        if (MODE == 1) {
          out[(long)row * N_EMBD + col] = v;
        } else {
          const u16 o = f2bf(v);
          const int which = col >> 10;  // 0=q 1=k 2=v
          const int cc = col & 1023;
          const int h = cc >> 6;
          const int dd = cc & 63;
          const int b = row >> 11;
          const int t = row & 2047;
          u16* dst = (which == 0) ? qo : ((which == 1) ? ko : vo);
          dst[(((long)(b * N_HEAD + h)) * SEQ + t) * HEAD_DIM + dd] = o;
        }
      }
    }
  }
}

// ======== flash attention (MFMA, online softmax) ========
// Pair-balanced: block p handles q-tiles p and 31-p (33 KV-tile units each).
// LDS double-buffered KV with register prefetch — ONE barrier per tile.
// Writes bf16 y IN-PLACE into the q buffer (each block reads only its own
// two Q tiles, before writing them).
#define BQ 64
#define BKV 64
#define KPAD 72
#define LOG2E 1.44269504f
#define NQT (SEQ / BQ)  // 32 q-tiles

__device__ __forceinline__ void load_kv(const u16* __restrict__ K,
                                        const u16* __restrict__ V, long bh,
                                        int kt, int tid, u16x8 kreg[2],
                                        u16x8 vreg[2]) {
#pragma unroll
  for (int i = 0; i < 2; ++i) {
    const int p = tid + 256 * i;
    const int kkey = p >> 3, kdg = p & 7;
    kreg[i] = *(const u16x8*)&K[(bh * SEQ + kt + kkey) * HEAD_DIM + kdg * 8];
    const int vkey = p & 63, vdg = p >> 6;
    vreg[i] = *(const u16x8*)&V[(bh * SEQ + kt + vkey) * HEAD_DIM + vdg * 8];
  }
}

__global__ __launch_bounds__(256) void flash_attn(u16* __restrict__ Qy,
                                                  const u16* __restrict__ K,
                                                  const u16* __restrict__ V) {
  const int pidx = blockIdx.x;  // 0..15
  const int h = blockIdx.y;
  const int b = blockIdx.z;
  const long bh = b * N_HEAD + h;
  const int tid = threadIdx.x;
  const int w = tid >> 6;
  const int l = tid & 63;
  const int m16 = l & 15;
  const int quad = l >> 4;

  __shared__ u16 Kl[2][BKV * KPAD];       // [buf][key][d]
  __shared__ u16 Vl[2][HEAD_DIM * KPAD];  // [buf][d][key] (transposed)
  __shared__ u16 Pl[4][16 * KPAD];        // per-wave [q][key]

  const float SC = 0.125f * LOG2E;  // scale folded into log2-space

  for (int ph = 0; ph < 2; ++ph) {
    const int iq = (ph == 0) ? pidx : (NQT - 1 - pidx);
    const int qb = iq * BQ;
    const int ntiles = iq + 1;

    bf16x8 qf[2];
    {
      const u16* qrow = Qy + (bh * SEQ + qb + w * 16 + m16) * HEAD_DIM;
      qf[0] = __builtin_bit_cast(bf16x8, *(const u16x8*)&qrow[quad * 8]);
      qf[1] = __builtin_bit_cast(bf16x8, *(const u16x8*)&qrow[32 + quad * 8]);
    }

    floatx4 Oacc[4];
#pragma unroll
    for (int t = 0; t < 4; ++t) Oacc[t] = (floatx4){0.f, 0.f, 0.f, 0.f};
    float mrow[4] = {-1e30f, -1e30f, -1e30f, -1e30f};
    float lrow[4] = {0.f, 0.f, 0.f, 0.f};

    u16x8 kreg[2], vreg[2];
    load_kv(K, V, bh, 0, tid, kreg, vreg);

    for (int it = 0; it < ntiles; ++it) {
      const int buf = it & 1;
      // ---- write prefetched regs -> LDS[buf] ----
#pragma unroll
      for (int i = 0; i < 2; ++i) {
        const int p = tid + 256 * i;
        const int kkey = p >> 3, kdg = p & 7;
        *(u16x8*)&Kl[buf][kkey * KPAD + kdg * 8] = kreg[i];
        const int vkey = p & 63, vdg = p >> 6;
#pragma unroll
        for (int j = 0; j < 8; ++j)
          Vl[buf][(vdg * 8 + j) * KPAD + vkey] = vreg[i][j];
      }
      __syncthreads();
      // ---- prefetch next tile (latency hidden behind compute) ----
      if (it + 1 < ntiles) load_kv(K, V, bh, (it + 1) * BKV, tid, kreg, vreg);

      // ---- S = Q K^T (pre-scaled into log2 space) ----
      floatx4 s[4];
#pragma unroll
      for (int j = 0; j < 4; ++j) s[j] = (floatx4){0.f, 0.f, 0.f, 0.f};
#pragma unroll
      for (int j = 0; j < 4; ++j)
#pragma unroll
        for (int kk = 0; kk < 2; ++kk) {
          const bf16x8 kf = __builtin_bit_cast(
              bf16x8, *(const u16x8*)&Kl[buf][(j * 16 + m16) * KPAD + kk * 32 +
                                              quad * 8]);
          s[j] = __builtin_amdgcn_mfma_f32_16x16x32_bf16(qf[kk], kf, s[j], 0,
                                                         0, 0);
        }
#pragma unroll
      for (int j = 0; j < 4; ++j)
#pragma unroll
        for (int r = 0; r < 4; ++r) s[j][r] *= SC;
      if (it == ntiles - 1) {
        const int qg = qb + w * 16 + quad * 4;
        const int kt = it * BKV;
#pragma unroll
        for (int j = 0; j < 4; ++j) {
          const int keyg = kt + j * 16 + m16;
#pragma unroll
          for (int r = 0; r < 4; ++r)
            if (keyg > qg + r) s[j][r] = -1e30f;
        }
      }

      // ---- online softmax (log2 space) ----
      float tm[4];
#pragma unroll
      for (int r = 0; r < 4; ++r)
        tm[r] = fmaxf(fmaxf(s[0][r], s[1][r]), fmaxf(s[2][r], s[3][r]));
#pragma unroll
      for (int d = 1; d < 16; d <<= 1)
#pragma unroll
        for (int r = 0; r < 4; ++r)
          tm[r] = fmaxf(tm[r], __shfl_xor(tm[r], d, 64));
      float mn[4], al[4];
#pragma unroll
      for (int r = 0; r < 4; ++r) {
        mn[r] = fmaxf(mrow[r], tm[r]);
        al[r] = exp2f(mrow[r] - mn[r]);
        mrow[r] = mn[r];
      }
      float ls[4] = {0.f, 0.f, 0.f, 0.f};
#pragma unroll
      for (int j = 0; j < 4; ++j) {
#pragma unroll
        for (int r = 0; r < 4; ++r) {
          const float p = exp2f(s[j][r] - mn[r]);
          ls[r] += p;
          Pl[w][(quad * 4 + r) * KPAD + j * 16 + m16] = f2bf(p);
        }
      }
#pragma unroll
      for (int d = 1; d < 16; d <<= 1)
#pragma unroll
        for (int r = 0; r < 4; ++r) ls[r] += __shfl_xor(ls[r], d, 64);
#pragma unroll
      for (int r = 0; r < 4; ++r) lrow[r] = lrow[r] * al[r] + ls[r];
#pragma unroll
      for (int t = 0; t < 4; ++t)
#pragma unroll
        for (int r = 0; r < 4; ++r) Oacc[t][r] *= al[r];

      // ---- O += P V (P via per-wave LDS round-trip) ----
      bf16x8 pf[2];
      pf[0] = __builtin_bit_cast(bf16x8,
                                 *(const u16x8*)&Pl[w][m16 * KPAD + quad * 8]);
      pf[1] = __builtin_bit_cast(
          bf16x8, *(const u16x8*)&Pl[w][m16 * KPAD + 32 + quad * 8]);
#pragma unroll
      for (int t = 0; t < 4; ++t)
#pragma unroll
        for (int kk = 0; kk < 2; ++kk) {
          const bf16x8 vf = __builtin_bit_cast(
              bf16x8, *(const u16x8*)&Vl[buf][(t * 16 + m16) * KPAD + kk * 32 +
                                              quad * 8]);
          Oacc[t] = __builtin_amdgcn_mfma_f32_16x16x32_bf16(pf[kk], vf,
                                                            Oacc[t], 0, 0, 0);
        }
      // no second barrier: next iter writes the other LDS buffer
    }

    // ---- epilogue: normalize, write bf16 y into the q buffer ----
    float inv[4];
#pragma unroll
    for (int r = 0; r < 4; ++r) inv[r] = 1.f / lrow[r];
#pragma unroll
    for (int t = 0; t < 4; ++t)
#pragma unroll
      for (int r = 0; r < 4; ++r) {
        const int row = qb + w * 16 + quad * 4 + r;
        Qy[(bh * SEQ + row) * HEAD_DIM + t * 16 + m16] =
            f2bf(Oacc[t][r] * inv[r]);
      }
    __syncthreads();  // phase B reuses LDS buffers
  }
}

// ======== launch ========
extern "C" void kernel_launch(void* const* d_in, const int* in_sizes, int n_in,
                              void* d_out, int out_size, void* d_ws,
                              size_t ws_size, hipStream_t stream) {
  const float* x = (const float*)d_in[0];
  const float* w_attn = (const float*)d_in[1];
  const float* b_attn = (const float*)d_in[2];
  const float* w_proj = (const float*)d_in[3];
  const float* b_proj = (const float*)d_in[4];
  float* out = (float*)d_out;

  // ws: q 8MB | k 8MB | v 8MB | wT_a 6MB | wT_p 2MB  = 32 MB
  char* ws = (char*)d_ws;
  const size_t SZ = (size_t)BATCH * N_HEAD * SEQ * HEAD_DIM * sizeof(u16);
  u16* q = (u16*)(ws);
  u16* k = (u16*)(ws + SZ);
  u16* v = (u16*)(ws + 2 * SZ);
  u16* wT_a = (u16*)(ws + 3 * SZ);
  u16* wT_p = (u16*)(ws + 3 * SZ + (size_t)3 * N_EMBD * N_EMBD * sizeof(u16));

  transpose_k<<<dim3(3 * N_EMBD / 32, N_EMBD / 32), dim3(32, 8), 0, stream>>>(
      w_attn, wT_a, N_EMBD, 3 * N_EMBD);
  transpose_k<<<dim3(N_EMBD / 32, N_EMBD / 32), dim3(32, 8), 0, stream>>>(
      w_proj, wT_p, N_EMBD, N_EMBD);

  gemm128<0><<<dim3(3 * N_EMBD / 128, M_ROWS / 128), 256, 0, stream>>>(
      x, wT_a, b_attn, nullptr, q, k, v, 3 * N_EMBD, N_EMBD);

  flash_attn<<<dim3(NQT / 2, N_HEAD, BATCH), 256, 0, stream>>>(q, k, v);

  gemm128<1><<<dim3(N_EMBD / 128, M_ROWS / 128), 256, 0, stream>>>(
      q, wT_p, b_proj, out, nullptr, nullptr, nullptr, N_EMBD, N_EMBD);
}

// Round 8
// 241.516 us; speedup vs baseline: 13.3618x; 1.0574x over previous
//
#include <hip/hip_runtime.h>

typedef unsigned short u16;
typedef u16 u16x8 __attribute__((ext_vector_type(8)));
typedef __bf16 bf16x8 __attribute__((ext_vector_type(8)));
typedef float floatx4 __attribute__((ext_vector_type(4)));

#define N_EMBD 1024
#define N_HEAD 16
#define HEAD_DIM 64
#define SEQ 2048
#define BATCH 2
#define M_ROWS (BATCH * SEQ)  // 4096

typedef __attribute__((address_space(1))) const unsigned char ga_t;
typedef __attribute__((address_space(3))) unsigned char la_t;

__device__ __forceinline__ float bf2f(u16 b) {
  return __uint_as_float(((unsigned)b) << 16);
}
__device__ __forceinline__ u16 f2bf(float f) {
  unsigned u = __float_as_uint(f);
  u += 0x7fffu + ((u >> 16) & 1u);  // RNE
  return (u16)(u >> 16);
}

// ======== convert: xb_bf16[i] = x_f32[i] (hoists cvt out of qkv K-loop) ====
__global__ __launch_bounds__(256) void convert_x(const float* __restrict__ x,
                                                 u16* __restrict__ xb) {
  const long i = ((long)blockIdx.x * 256 + threadIdx.x) * 8;
  const float4 f0 = *(const float4*)&x[i];
  const float4 f1 = *(const float4*)&x[i + 4];
  u16x8 p;
  p[0] = f2bf(f0.x); p[1] = f2bf(f0.y); p[2] = f2bf(f0.z); p[3] = f2bf(f0.w);
  p[4] = f2bf(f1.x); p[5] = f2bf(f1.y); p[6] = f2bf(f1.z); p[7] = f2bf(f1.w);
  *(u16x8*)&xb[i] = p;
}

// ======== transpose+convert: out_bf16[C][R] = in_f32[R][C] ========
__global__ __launch_bounds__(256) void transpose_k(const float* __restrict__ in,
                                                   u16* __restrict__ out,
                                                   int R, int C) {
  __shared__ u16 tile[32][33];
  int bx = blockIdx.x * 32;
  int by = blockIdx.y * 32;
  int tx = threadIdx.x;
  int ty = threadIdx.y;
#pragma unroll
  for (int j = 0; j < 32; j += 8)
    tile[ty + j][tx] = f2bf(in[(long)(by + ty + j) * C + bx + tx]);
  __syncthreads();
#pragma unroll
  for (int j = 0; j < 32; j += 8)
    out[(long)(bx + ty + j) * R + by + tx] = tile[tx][ty + j];
}

// ======== 128x128 GEMM, m97-style global_load_lds staging ========
// A bf16: MODE 0 = xb [M,K] row-major; MODE 1 = q-buffer [B,H,T,D] remap.
// B bf16 pre-transposed [N][K].
// Epilogue: MODE 0 scatters bf16 q/k/v; MODE 1 writes fp32 out + bias.
#define BK 32

template <int MODE>
__global__ __launch_bounds__(256) void gemm128(
    const u16* __restrict__ A, const u16* __restrict__ Bt,
    const float* __restrict__ bias, float* __restrict__ out,
    u16* __restrict__ qo, u16* __restrict__ ko, u16* __restrict__ vo, int N,
    int K) {
  __shared__ u16 As[128 * BK];
  __shared__ u16 Bs[128 * BK];
  const int tid = threadIdx.x;
  const int bm = blockIdx.y * 128;
  const int bn = blockIdx.x * 128;
  const int w = tid >> 6;
  const int l = tid & 63;
  const int wm = (w >> 1) * 64;
  const int wn = (w & 1) * 64;
  const int m16 = l & 15;
  const int quad = l >> 4;
  const int lrow = l >> 2;         // 0..15 (within wave's 16-row group)
  const int lcol = (l & 3) * 8;    // 0,8,16,24

  floatx4 acc[4][4];
#pragma unroll
  for (int i = 0; i < 4; ++i)
#pragma unroll
    for (int j = 0; j < 4; ++j) acc[i][j] = (floatx4){0.f, 0.f, 0.f, 0.f};

  for (int kt = 0; kt < K; kt += BK) {
    // ---- async stage: 2 x (A,B) global_load_lds_dwordx4 per thread ----
#pragma unroll
    for (int p = 0; p < 2; ++p) {
      const int arow = p * 64 + w * 16;  // wave-uniform LDS row base
      long gA;
      if (MODE == 0) {
        gA = (long)(bm + arow + lrow) * K + kt + lcol;
      } else {
        const int m = bm + arow + lrow;
        const int b = m >> 11, t = m & 2047;
        const int k0 = kt + lcol;
        const int head = k0 >> 6, dd = k0 & 63;  // BK=32 never crosses a head
        gA = (((long)(b * N_HEAD + head)) * SEQ + t) * HEAD_DIM + dd;
      }
      __builtin_amdgcn_global_load_lds((ga_t*)(A + gA), (la_t*)&As[arow * BK],
                                       16, 0, 0);
      const long gB = (long)(bn + arow + lrow) * K + kt + lcol;
      __builtin_amdgcn_global_load_lds((ga_t*)(Bt + gB), (la_t*)&Bs[arow * BK],
                                       16, 0, 0);
    }
    __syncthreads();  // drains vmcnt before any wave proceeds

    bf16x8 af[4], bfr[4];
#pragma unroll
    for (int i = 0; i < 4; ++i)
      af[i] = __builtin_bit_cast(
          bf16x8, *(const u16x8*)&As[(wm + i * 16 + m16) * BK + quad * 8]);
#pragma unroll
    for (int j = 0; j < 4; ++j)
      bfr[j] = __builtin_bit_cast(
          bf16x8, *(const u16x8*)&Bs[(wn + j * 16 + m16) * BK + quad * 8]);
#pragma unroll
    for (int i = 0; i < 4; ++i)
#pragma unroll
      for (int j = 0; j < 4; ++j)
        acc[i][j] = __builtin_amdgcn_mfma_f32_16x16x32_bf16(af[i], bfr[j],
                                                            acc[i][j], 0, 0, 0);
    __syncthreads();
  }

#pragma unroll
  for (int i = 0; i < 4; ++i) {
#pragma unroll
    for (int j = 0; j < 4; ++j) {
      const int col = bn + wn + j * 16 + m16;
      const float bv = bias[col];
#pragma unroll
      for (int r = 0; r < 4; ++r) {
        const int row = bm + wm + i * 16 + quad * 4 + r;
        const float v = acc[i][j][r] + bv;
        if (MODE == 1) {
          out[(long)row * N_EMBD + col] = v;
        } else {
          const u16 o = f2bf(v);
          const int which = col >> 10;  // 0=q 1=k 2=v
          const int cc = col & 1023;
          const int h = cc >> 6;
          const int dd = cc & 63;
          const int b = row >> 11;
          const int t = row & 2047;
          u16* dst = (which == 0) ? qo : ((which == 1) ? ko : vo);
          dst[(((long)(b * N_HEAD + h)) * SEQ + t) * HEAD_DIM + dd] = o;
        }
      }
    }
  }
}

// ======== flash attention (unchanged from round 7) ========
#define BQ 64
#define BKV 64
#define KPAD 72
#define LOG2E 1.44269504f
#define NQT (SEQ / BQ)  // 32 q-tiles

__device__ __forceinline__ void load_kv(const u16* __restrict__ K,
                                        const u16* __restrict__ V, long bh,
                                        int kt, int tid, u16x8 kreg[2],
                                        u16x8 vreg[2]) {
#pragma unroll
  for (int i = 0; i < 2; ++i) {
    const int p = tid + 256 * i;
    const int kkey = p >> 3, kdg = p & 7;
    kreg[i] = *(const u16x8*)&K[(bh * SEQ + kt + kkey) * HEAD_DIM + kdg * 8];
    const int vkey = p & 63, vdg = p >> 6;
    vreg[i] = *(const u16x8*)&V[(bh * SEQ + kt + vkey) * HEAD_DIM + vdg * 8];
  }
}

__global__ __launch_bounds__(256) void flash_attn(u16* __restrict__ Qy,
                                                  const u16* __restrict__ K,
                                                  const u16* __restrict__ V) {
  const int pidx = blockIdx.x;  // 0..15
  const int h = blockIdx.y;
  const int b = blockIdx.z;
  const long bh = b * N_HEAD + h;
  const int tid = threadIdx.x;
  const int w = tid >> 6;
  const int l = tid & 63;
  const int m16 = l & 15;
  const int quad = l >> 4;

  __shared__ u16 Kl[2][BKV * KPAD];
  __shared__ u16 Vl[2][HEAD_DIM * KPAD];
  __shared__ u16 Pl[4][16 * KPAD];

  const float SC = 0.125f * LOG2E;

  for (int ph = 0; ph < 2; ++ph) {
    const int iq = (ph == 0) ? pidx : (NQT - 1 - pidx);
    const int qb = iq * BQ;
    const int ntiles = iq + 1;

    bf16x8 qf[2];
    {
      const u16* qrow = Qy + (bh * SEQ + qb + w * 16 + m16) * HEAD_DIM;
      qf[0] = __builtin_bit_cast(bf16x8, *(const u16x8*)&qrow[quad * 8]);
      qf[1] = __builtin_bit_cast(bf16x8, *(const u16x8*)&qrow[32 + quad * 8]);
    }

    floatx4 Oacc[4];
#pragma unroll
    for (int t = 0; t < 4; ++t) Oacc[t] = (floatx4){0.f, 0.f, 0.f, 0.f};
    float mrow[4] = {-1e30f, -1e30f, -1e30f, -1e30f};
    float lrow[4] = {0.f, 0.f, 0.f, 0.f};

    u16x8 kreg[2], vreg[2];
    load_kv(K, V, bh, 0, tid, kreg, vreg);

    for (int it = 0; it < ntiles; ++it) {
      const int buf = it & 1;
#pragma unroll
      for (int i = 0; i < 2; ++i) {
        const int p = tid + 256 * i;
        const int kkey = p >> 3, kdg = p & 7;
        *(u16x8*)&Kl[buf][kkey * KPAD + kdg * 8] = kreg[i];
        const int vkey = p & 63, vdg = p >> 6;
#pragma unroll
        for (int j = 0; j < 8; ++j)
          Vl[buf][(vdg * 8 + j) * KPAD + vkey] = vreg[i][j];
      }
      __syncthreads();
      if (it + 1 < ntiles) load_kv(K, V, bh, (it + 1) * BKV, tid, kreg, vreg);

      floatx4 s[4];
#pragma unroll
      for (int j = 0; j < 4; ++j) s[j] = (floatx4){0.f, 0.f, 0.f, 0.f};
#pragma unroll
      for (int j = 0; j < 4; ++j)
#pragma unroll
        for (int kk = 0; kk < 2; ++kk) {
          const bf16x8 kf = __builtin_bit_cast(
              bf16x8, *(const u16x8*)&Kl[buf][(j * 16 + m16) * KPAD + kk * 32 +
                                              quad * 8]);
          s[j] = __builtin_amdgcn_mfma_f32_16x16x32_bf16(qf[kk], kf, s[j], 0,
                                                         0, 0);
        }
#pragma unroll
      for (int j = 0; j < 4; ++j)
#pragma unroll
        for (int r = 0; r < 4; ++r) s[j][r] *= SC;
      if (it == ntiles - 1) {
        const int qg = qb + w * 16 + quad * 4;
        const int kt = it * BKV;
#pragma unroll
        for (int j = 0; j < 4; ++j) {
          const int keyg = kt + j * 16 + m16;
#pragma unroll
          for (int r = 0; r < 4; ++r)
            if (keyg > qg + r) s[j][r] = -1e30f;
        }
      }

      float tm[4];
#pragma unroll
      for (int r = 0; r < 4; ++r)
        tm[r] = fmaxf(fmaxf(s[0][r], s[1][r]), fmaxf(s[2][r], s[3][r]));
#pragma unroll
      for (int d = 1; d < 16; d <<= 1)
#pragma unroll
        for (int r = 0; r < 4; ++r)
          tm[r] = fmaxf(tm[r], __shfl_xor(tm[r], d, 64));
      float mn[4], al[4];
#pragma unroll
      for (int r = 0; r < 4; ++r) {
        mn[r] = fmaxf(mrow[r], tm[r]);
        al[r] = exp2f(mrow[r] - mn[r]);
        mrow[r] = mn[r];
      }
      float ls[4] = {0.f, 0.f, 0.f, 0.f};
#pragma unroll
      for (int j = 0; j < 4; ++j) {
#pragma unroll
        for (int r = 0; r < 4; ++r) {
          const float p = exp2f(s[j][r] - mn[r]);
          ls[r] += p;
          Pl[w][(quad * 4 + r) * KPAD + j * 16 + m16] = f2bf(p);
        }
      }
#pragma unroll
      for (int d = 1; d < 16; d <<= 1)
#pragma unroll
        for (int r = 0; r < 4; ++r) ls[r] += __shfl_xor(ls[r], d, 64);
#pragma unroll
      for (int r = 0; r < 4; ++r) lrow[r] = lrow[r] * al[r] + ls[r];
#pragma unroll
      for (int t = 0; t < 4; ++t)
#pragma unroll
        for (int r = 0; r < 4; ++r) Oacc[t][r] *= al[r];

      bf16x8 pf[2];
      pf[0] = __builtin_bit_cast(bf16x8,
                                 *(const u16x8*)&Pl[w][m16 * KPAD + quad * 8]);
      pf[1] = __builtin_bit_cast(
          bf16x8, *(const u16x8*)&Pl[w][m16 * KPAD + 32 + quad * 8]);
#pragma unroll
      for (int t = 0; t < 4; ++t)
#pragma unroll
        for (int kk = 0; kk < 2; ++kk) {
          const bf16x8 vf = __builtin_bit_cast(
              bf16x8, *(const u16x8*)&Vl[buf][(t * 16 + m16) * KPAD + kk * 32 +
                                              quad * 8]);
          Oacc[t] = __builtin_amdgcn_mfma_f32_16x16x32_bf16(pf[kk], vf,
                                                            Oacc[t], 0, 0, 0);
        }
    }

    float inv[4];
#pragma unroll
    for (int r = 0; r < 4; ++r) inv[r] = 1.f / lrow[r];
#pragma unroll
    for (int t = 0; t < 4; ++t)
#pragma unroll
      for (int r = 0; r < 4; ++r) {
        const int row = qb + w * 16 + quad * 4 + r;
        Qy[(bh * SEQ + row) * HEAD_DIM + t * 16 + m16] =
            f2bf(Oacc[t][r] * inv[r]);
      }
    __syncthreads();
  }
}

// ======== launch ========
extern "C" void kernel_launch(void* const* d_in, const int* in_sizes, int n_in,
                              void* d_out, int out_size, void* d_ws,
                              size_t ws_size, hipStream_t stream) {
  const float* x = (const float*)d_in[0];
  const float* w_attn = (const float*)d_in[1];
  const float* b_attn = (const float*)d_in[2];
  const float* w_proj = (const float*)d_in[3];
  const float* b_proj = (const float*)d_in[4];
  float* out = (float*)d_out;

  // ws: q 8 | k 8 | v 8 | wT_a 6 | wT_p 2 | xb 8  = 40 MB
  char* ws = (char*)d_ws;
  const size_t SZ = (size_t)BATCH * N_HEAD * SEQ * HEAD_DIM * sizeof(u16);
  u16* q = (u16*)(ws);
  u16* k = (u16*)(ws + SZ);
  u16* v = (u16*)(ws + 2 * SZ);
  u16* wT_a = (u16*)(ws + 3 * SZ);
  u16* wT_p = (u16*)(ws + 3 * SZ + (size_t)3 * N_EMBD * N_EMBD * sizeof(u16));
  u16* xb = (u16*)(ws + 3 * SZ + (size_t)4 * N_EMBD * N_EMBD * sizeof(u16));

  convert_x<<<(long)M_ROWS * N_EMBD / 8 / 256, 256, 0, stream>>>(x, xb);
  transpose_k<<<dim3(3 * N_EMBD / 32, N_EMBD / 32), dim3(32, 8), 0, stream>>>(
      w_attn, wT_a, N_EMBD, 3 * N_EMBD);
  transpose_k<<<dim3(N_EMBD / 32, N_EMBD / 32), dim3(32, 8), 0, stream>>>(
      w_proj, wT_p, N_EMBD, N_EMBD);

  gemm128<0><<<dim3(3 * N_EMBD / 128, M_ROWS / 128), 256, 0, stream>>>(
      xb, wT_a, b_attn, nullptr, q, k, v, 3 * N_EMBD, N_EMBD);

  flash_attn<<<dim3(NQT / 2, N_HEAD, BATCH), 256, 0, stream>>>(q, k, v);

  gemm128<1><<<dim3(N_EMBD / 128, M_ROWS / 128), 256, 0, stream>>>(
      q, wT_p, b_proj, out, nullptr, nullptr, nullptr, N_EMBD, N_EMBD);
}

// Round 9
// 224.141 us; speedup vs baseline: 14.3976x; 1.0775x over previous
//
#include <hip/hip_runtime.h>

typedef unsigned short u16;
typedef u16 u16x4 __attribute__((ext_vector_type(4)));
typedef u16 u16x8 __attribute__((ext_vector_type(8)));
typedef __bf16 bf16x8 __attribute__((ext_vector_type(8)));
typedef float floatx4 __attribute__((ext_vector_type(4)));

#define N_EMBD 1024
#define N_HEAD 16
#define HEAD_DIM 64
#define SEQ 2048
#define BATCH 2
#define M_ROWS (BATCH * SEQ)  // 4096

typedef __attribute__((address_space(1))) const unsigned char ga_t;
typedef __attribute__((address_space(3))) unsigned char la_t;

__device__ __forceinline__ float bf2f(u16 b) {
  return __uint_as_float(((unsigned)b) << 16);
}
__device__ __forceinline__ u16 f2bf(float f) {
  unsigned u = __float_as_uint(f);
  u += 0x7fffu + ((u >> 16) & 1u);  // RNE
  return (u16)(u >> 16);
}

// ======== convert: xb_bf16[i] = x_f32[i] ========
__global__ __launch_bounds__(256) void convert_x(const float* __restrict__ x,
                                                 u16* __restrict__ xb) {
  const long i = ((long)blockIdx.x * 256 + threadIdx.x) * 8;
  const float4 f0 = *(const float4*)&x[i];
  const float4 f1 = *(const float4*)&x[i + 4];
  u16x8 p;
  p[0] = f2bf(f0.x); p[1] = f2bf(f0.y); p[2] = f2bf(f0.z); p[3] = f2bf(f0.w);
  p[4] = f2bf(f1.x); p[5] = f2bf(f1.y); p[6] = f2bf(f1.z); p[7] = f2bf(f1.w);
  *(u16x8*)&xb[i] = p;
}

// ======== transpose+convert: out_bf16[C][R] = in_f32[R][C] ========
__global__ __launch_bounds__(256) void transpose_k(const float* __restrict__ in,
                                                   u16* __restrict__ out,
                                                   int R, int C) {
  __shared__ u16 tile[32][33];
  int bx = blockIdx.x * 32;
  int by = blockIdx.y * 32;
  int tx = threadIdx.x;
  int ty = threadIdx.y;
#pragma unroll
  for (int j = 0; j < 32; j += 8)
    tile[ty + j][tx] = f2bf(in[(long)(by + ty + j) * C + bx + tx]);
  __syncthreads();
#pragma unroll
  for (int j = 0; j < 32; j += 8)
    out[(long)(bx + ty + j) * R + by + tx] = tile[tx][ty + j];
}

// ======== 128x128 GEMM, m97-style global_load_lds staging (unchanged) =====
#define BK 32

template <int MODE>
__global__ __launch_bounds__(256) void gemm128(
    const u16* __restrict__ A, const u16* __restrict__ Bt,
    const float* __restrict__ bias, float* __restrict__ out,
    u16* __restrict__ qo, u16* __restrict__ ko, u16* __restrict__ vo, int N,
    int K) {
  __shared__ u16 As[128 * BK];
  __shared__ u16 Bs[128 * BK];
  const int tid = threadIdx.x;
  const int bm = blockIdx.y * 128;
  const int bn = blockIdx.x * 128;
  const int w = tid >> 6;
  const int l = tid & 63;
  const int wm = (w >> 1) * 64;
  const int wn = (w & 1) * 64;
  const int m16 = l & 15;
  const int quad = l >> 4;
  const int lrow = l >> 2;
  const int lcol = (l & 3) * 8;

  floatx4 acc[4][4];
#pragma unroll
  for (int i = 0; i < 4; ++i)
#pragma unroll
    for (int j = 0; j < 4; ++j) acc[i][j] = (floatx4){0.f, 0.f, 0.f, 0.f};

  for (int kt = 0; kt < K; kt += BK) {
#pragma unroll
    for (int p = 0; p < 2; ++p) {
      const int arow = p * 64 + w * 16;
      long gA;
      if (MODE == 0) {
        gA = (long)(bm + arow + lrow) * K + kt + lcol;
      } else {
        const int m = bm + arow + lrow;
        const int b = m >> 11, t = m & 2047;
        const int k0 = kt + lcol;
        const int head = k0 >> 6, dd = k0 & 63;
        gA = (((long)(b * N_HEAD + head)) * SEQ + t) * HEAD_DIM + dd;
      }
      __builtin_amdgcn_global_load_lds((ga_t*)(A + gA), (la_t*)&As[arow * BK],
                                       16, 0, 0);
      const long gB = (long)(bn + arow + lrow) * K + kt + lcol;
      __builtin_amdgcn_global_load_lds((ga_t*)(Bt + gB), (la_t*)&Bs[arow * BK],
                                       16, 0, 0);
    }
    __syncthreads();

    bf16x8 af[4], bfr[4];
#pragma unroll
    for (int i = 0; i < 4; ++i)
      af[i] = __builtin_bit_cast(
          bf16x8, *(const u16x8*)&As[(wm + i * 16 + m16) * BK + quad * 8]);
#pragma unroll
    for (int j = 0; j < 4; ++j)
      bfr[j] = __builtin_bit_cast(
          bf16x8, *(const u16x8*)&Bs[(wn + j * 16 + m16) * BK + quad * 8]);
#pragma unroll
    for (int i = 0; i < 4; ++i)
#pragma unroll
      for (int j = 0; j < 4; ++j)
        acc[i][j] = __builtin_amdgcn_mfma_f32_16x16x32_bf16(af[i], bfr[j],
                                                            acc[i][j], 0, 0, 0);
    __syncthreads();
  }

#pragma unroll
  for (int i = 0; i < 4; ++i) {
#pragma unroll
    for (int j = 0; j < 4; ++j) {
      const int col = bn + wn + j * 16 + m16;
      const float bv = bias[col];
#pragma unroll
      for (int r = 0; r < 4; ++r) {
        const int row = bm + wm + i * 16 + quad * 4 + r;
        const float v = acc[i][j][r] + bv;
        if (MODE == 1) {
          out[(long)row * N_EMBD + col] = v;
        } else {
          const u16 o = f2bf(v);
          const int which = col >> 10;  // 0=q 1=k 2=v
          const int cc = col & 1023;
          const int h = cc >> 6;
          const int dd = cc & 63;
          const int b = row >> 11;
          const int t = row & 2047;
          u16* dst = (which == 0) ? qo : ((which == 1) ? ko : vo);
          dst[(((long)(b * N_HEAD + h)) * SEQ + t) * HEAD_DIM + dd] = o;
        }
      }
    }
  }
}

// ======== flash attention — S^T formulation ========
// S^T = K·Q^T (operand swap): C-layout col = q = lane&15, row = key.
// Softmax over keys = in-register reduce + 2 shuffle steps; per-lane scalar
// m/l/alpha state; vectorized P-stores (b64) and O^T epilogue stores.
#define BQ 64
#define BKV 64
#define KPAD 72
#define LOG2E 1.44269504f
#define NQT (SEQ / BQ)  // 32 q-tiles

__device__ __forceinline__ void load_kv(const u16* __restrict__ K,
                                        const u16* __restrict__ V, long bh,
                                        int kt, int tid, u16x8 kreg[2],
                                        u16x8 vreg[2]) {
#pragma unroll
  for (int i = 0; i < 2; ++i) {
    const int p = tid + 256 * i;
    const int kkey = p >> 3, kdg = p & 7;
    kreg[i] = *(const u16x8*)&K[(bh * SEQ + kt + kkey) * HEAD_DIM + kdg * 8];
    const int vkey = p & 63, vdg = p >> 6;
    vreg[i] = *(const u16x8*)&V[(bh * SEQ + kt + vkey) * HEAD_DIM + vdg * 8];
  }
}

__global__ __launch_bounds__(256) void flash_attn(u16* __restrict__ Qy,
                                                  const u16* __restrict__ K,
                                                  const u16* __restrict__ V) {
  const int pidx = blockIdx.x;  // 0..15
  const int h = blockIdx.y;
  const int b = blockIdx.z;
  const long bh = b * N_HEAD + h;
  const int tid = threadIdx.x;
  const int w = tid >> 6;
  const int l = tid & 63;
  const int m16 = l & 15;
  const int quad = l >> 4;

  __shared__ u16 Kl[2][BKV * KPAD];       // [buf][key][d]
  __shared__ u16 Vl[2][HEAD_DIM * KPAD];  // [buf][d][key]
  __shared__ u16 Pl[4][16 * KPAD];        // per-wave [q][key]

  const float SC = 0.125f * LOG2E;

  for (int ph = 0; ph < 2; ++ph) {
    const int iq = (ph == 0) ? pidx : (NQT - 1 - pidx);
    const int qb = iq * BQ;
    const int ntiles = iq + 1;
    const int qglob = qb + w * 16 + m16;  // this lane's q row (= n index)

    bf16x8 qf[2];
    {
      const u16* qrow = Qy + (bh * SEQ + qglob) * HEAD_DIM;
      qf[0] = __builtin_bit_cast(bf16x8, *(const u16x8*)&qrow[quad * 8]);
      qf[1] = __builtin_bit_cast(bf16x8, *(const u16x8*)&qrow[32 + quad * 8]);
    }

    floatx4 Oacc[4];  // O^T: col=q=m16, row=d = t*16 + quad*4 + r
#pragma unroll
    for (int t = 0; t < 4; ++t) Oacc[t] = (floatx4){0.f, 0.f, 0.f, 0.f};
    float mrow = -1e30f, lrow = 0.f;

    u16x8 kreg[2], vreg[2];
    load_kv(K, V, bh, 0, tid, kreg, vreg);

    for (int it = 0; it < ntiles; ++it) {
      const int buf = it & 1;
#pragma unroll
      for (int i = 0; i < 2; ++i) {
        const int p = tid + 256 * i;
        const int kkey = p >> 3, kdg = p & 7;
        *(u16x8*)&Kl[buf][kkey * KPAD + kdg * 8] = kreg[i];
        const int vkey = p & 63, vdg = p >> 6;
#pragma unroll
        for (int j = 0; j < 8; ++j)
          Vl[buf][(vdg * 8 + j) * KPAD + vkey] = vreg[i][j];
      }
      __syncthreads();
      if (it + 1 < ntiles) load_kv(K, V, bh, (it + 1) * BKV, tid, kreg, vreg);

      // ---- S^T = K Q^T : s[j] covers keys [kt+16j, kt+16j+16) x 16 q ----
      floatx4 s[4];
#pragma unroll
      for (int j = 0; j < 4; ++j) s[j] = (floatx4){0.f, 0.f, 0.f, 0.f};
#pragma unroll
      for (int j = 0; j < 4; ++j)
#pragma unroll
        for (int kk = 0; kk < 2; ++kk) {
          const bf16x8 kf = __builtin_bit_cast(
              bf16x8, *(const u16x8*)&Kl[buf][(j * 16 + m16) * KPAD + kk * 32 +
                                              quad * 8]);
          s[j] = __builtin_amdgcn_mfma_f32_16x16x32_bf16(kf, qf[kk], s[j], 0,
                                                         0, 0);
        }
#pragma unroll
      for (int j = 0; j < 4; ++j)
#pragma unroll
        for (int r = 0; r < 4; ++r) s[j][r] *= SC;
      if (it == ntiles - 1) {
        const int kt = it * BKV;
#pragma unroll
        for (int j = 0; j < 4; ++j) {
          const int key0 = kt + j * 16 + quad * 4;
#pragma unroll
          for (int r = 0; r < 4; ++r)
            if (key0 + r > qglob) s[j][r] = -1e30f;
        }
      }

      // ---- online softmax: per-lane over 16 regs, then 2 shuffle steps ----
      float tm = s[0][0];
#pragma unroll
      for (int j = 0; j < 4; ++j)
#pragma unroll
        for (int r = 0; r < 4; ++r) tm = fmaxf(tm, s[j][r]);
      tm = fmaxf(tm, __shfl_xor(tm, 16, 64));
      tm = fmaxf(tm, __shfl_xor(tm, 32, 64));
      const float mn = fmaxf(mrow, tm);
      const float al = exp2f(mrow - mn);
      mrow = mn;

      float ls = 0.f;
#pragma unroll
      for (int j = 0; j < 4; ++j) {
        u16x4 pk;
#pragma unroll
        for (int r = 0; r < 4; ++r) {
          const float p = exp2f(s[j][r] - mn);
          ls += p;
          pk[r] = f2bf(p);
        }
        *(u16x4*)&Pl[w][m16 * KPAD + j * 16 + quad * 4] = pk;
      }
      ls += __shfl_xor(ls, 16, 64);
      ls += __shfl_xor(ls, 32, 64);
      lrow = lrow * al + ls;
#pragma unroll
      for (int t = 0; t < 4; ++t)
#pragma unroll
        for (int r = 0; r < 4; ++r) Oacc[t][r] *= al;

      // ---- O^T += V^T P^T ----
      bf16x8 pf[2];
      pf[0] = __builtin_bit_cast(bf16x8,
                                 *(const u16x8*)&Pl[w][m16 * KPAD + quad * 8]);
      pf[1] = __builtin_bit_cast(
          bf16x8, *(const u16x8*)&Pl[w][m16 * KPAD + 32 + quad * 8]);
#pragma unroll
      for (int t = 0; t < 4; ++t)
#pragma unroll
        for (int kk = 0; kk < 2; ++kk) {
          const bf16x8 vf = __builtin_bit_cast(
              bf16x8, *(const u16x8*)&Vl[buf][(t * 16 + m16) * KPAD + kk * 32 +
                                              quad * 8]);
          Oacc[t] = __builtin_amdgcn_mfma_f32_16x16x32_bf16(vf, pf[kk],
                                                            Oacc[t], 0, 0, 0);
        }
    }

    // ---- epilogue: O^T lane holds (d = t*16+quad*4+r, q = m16) ----
    const float invl = 1.f / lrow;
#pragma unroll
    for (int t = 0; t < 4; ++t) {
      u16x4 pk;
#pragma unroll
      for (int r = 0; r < 4; ++r) pk[r] = f2bf(Oacc[t][r] * invl);
      *(u16x4*)&Qy[(bh * SEQ + qglob) * HEAD_DIM + t * 16 + quad * 4] = pk;
    }
    __syncthreads();  // phase B reuses LDS buffers
  }
}

// ======== launch ========
extern "C" void kernel_launch(void* const* d_in, const int* in_sizes, int n_in,
                              void* d_out, int out_size, void* d_ws,
                              size_t ws_size, hipStream_t stream) {
  const float* x = (const float*)d_in[0];
  const float* w_attn = (const float*)d_in[1];
  const float* b_attn = (const float*)d_in[2];
  const float* w_proj = (const float*)d_in[3];
  const float* b_proj = (const float*)d_in[4];
  float* out = (float*)d_out;

  // ws: q 8 | k 8 | v 8 | wT_a 6 | wT_p 2 | xb 8  = 40 MB
  char* ws = (char*)d_ws;
  const size_t SZ = (size_t)BATCH * N_HEAD * SEQ * HEAD_DIM * sizeof(u16);
  u16* q = (u16*)(ws);
  u16* k = (u16*)(ws + SZ);
  u16* v = (u16*)(ws + 2 * SZ);
  u16* wT_a = (u16*)(ws + 3 * SZ);
  u16* wT_p = (u16*)(ws + 3 * SZ + (size_t)3 * N_EMBD * N_EMBD * sizeof(u16));
  u16* xb = (u16*)(ws + 3 * SZ + (size_t)4 * N_EMBD * N_EMBD * sizeof(u16));

  convert_x<<<(long)M_ROWS * N_EMBD / 8 / 256, 256, 0, stream>>>(x, xb);
  transpose_k<<<dim3(3 * N_EMBD / 32, N_EMBD / 32), dim3(32, 8), 0, stream>>>(
      w_attn, wT_a, N_EMBD, 3 * N_EMBD);
  transpose_k<<<dim3(N_EMBD / 32, N_EMBD / 32), dim3(32, 8), 0, stream>>>(
      w_proj, wT_p, N_EMBD, N_EMBD);

  gemm128<0><<<dim3(3 * N_EMBD / 128, M_ROWS / 128), 256, 0, stream>>>(
      xb, wT_a, b_attn, nullptr, q, k, v, 3 * N_EMBD, N_EMBD);

  flash_attn<<<dim3(NQT / 2, N_HEAD, BATCH), 256, 0, stream>>>(q, k, v);

  gemm128<1><<<dim3(N_EMBD / 128, M_ROWS / 128), 256, 0, stream>>>(
      q, wT_p, b_proj, out, nullptr, nullptr, nullptr, N_EMBD, N_EMBD);
}

// Round 10
// 197.310 us; speedup vs baseline: 16.3555x; 1.1360x over previous
//
#include <hip/hip_runtime.h>

typedef unsigned short u16;
typedef u16 u16x4 __attribute__((ext_vector_type(4)));
typedef u16 u16x8 __attribute__((ext_vector_type(8)));
typedef __bf16 bf16x8 __attribute__((ext_vector_type(8)));
typedef float floatx4 __attribute__((ext_vector_type(4)));

#define N_EMBD 1024
#define N_HEAD 16
#define HEAD_DIM 64
#define SEQ 2048
#define BATCH 2
#define M_ROWS (BATCH * SEQ)  // 4096

typedef __attribute__((address_space(1))) const unsigned char ga_t;
typedef __attribute__((address_space(3))) unsigned char la_t;

#if __has_builtin(__builtin_amdgcn_exp2f)
#define EXP2(x) __builtin_amdgcn_exp2f(x)
#else
#define EXP2(x) exp2f(x)
#endif

__device__ __forceinline__ float bf2f(u16 b) {
  return __uint_as_float(((unsigned)b) << 16);
}
__device__ __forceinline__ u16 f2bf(float f) {
  unsigned u = __float_as_uint(f);
  u += 0x7fffu + ((u >> 16) & 1u);  // RNE
  return (u16)(u >> 16);
}

// ======== convert: xb_bf16[i] = x_f32[i] ========
__global__ __launch_bounds__(256) void convert_x(const float* __restrict__ x,
                                                 u16* __restrict__ xb) {
  const long i = ((long)blockIdx.x * 256 + threadIdx.x) * 8;
  const float4 f0 = *(const float4*)&x[i];
  const float4 f1 = *(const float4*)&x[i + 4];
  u16x8 p;
  p[0] = f2bf(f0.x); p[1] = f2bf(f0.y); p[2] = f2bf(f0.z); p[3] = f2bf(f0.w);
  p[4] = f2bf(f1.x); p[5] = f2bf(f1.y); p[6] = f2bf(f1.z); p[7] = f2bf(f1.w);
  *(u16x8*)&xb[i] = p;
}

// ======== merged transpose+convert for both weights ========
// blocks x<96: w_attn (C=3072); x>=96: w_proj (C=1024). R=1024 both.
__global__ __launch_bounds__(256) void transpose2(
    const float* __restrict__ wa, const float* __restrict__ wp,
    u16* __restrict__ outa, u16* __restrict__ outp) {
  __shared__ u16 tile[32][33];
  const int R = N_EMBD;
  const float* in;
  u16* out;
  int C, bx;
  if (blockIdx.x < 96) {
    in = wa; out = outa; C = 3 * N_EMBD; bx = blockIdx.x * 32;
  } else {
    in = wp; out = outp; C = N_EMBD; bx = (blockIdx.x - 96) * 32;
  }
  const int by = blockIdx.y * 32;
  const int tx = threadIdx.x;
  const int ty = threadIdx.y;
#pragma unroll
  for (int j = 0; j < 32; j += 8)
    tile[ty + j][tx] = f2bf(in[(long)(by + ty + j) * C + bx + tx]);
  __syncthreads();
#pragma unroll
  for (int j = 0; j < 32; j += 8)
    out[(long)(bx + ty + j) * R + by + tx] = tile[tx][ty + j];
}

// ======== 128x128 GEMM, m97-style global_load_lds staging ========
// MODE 0: A=xb [M,K]; epilogue scatters q/k (bf16 [B,H,T,D]) and vT [B,H,D,T].
// MODE 1: A=q-buffer remap; epilogue writes fp32 out + bias.
#define BK 32

template <int MODE>
__global__ __launch_bounds__(256) void gemm128(
    const u16* __restrict__ A, const u16* __restrict__ Bt,
    const float* __restrict__ bias, float* __restrict__ out,
    u16* __restrict__ qo, u16* __restrict__ ko, u16* __restrict__ vo, int N,
    int K) {
  __shared__ u16 As[128 * BK];
  __shared__ u16 Bs[128 * BK];
  const int tid = threadIdx.x;
  const int bm = blockIdx.y * 128;
  const int bn = blockIdx.x * 128;
  const int w = tid >> 6;
  const int l = tid & 63;
  const int wm = (w >> 1) * 64;
  const int wn = (w & 1) * 64;
  const int m16 = l & 15;
  const int quad = l >> 4;
  const int lrow = l >> 2;
  const int lcol = (l & 3) * 8;

  floatx4 acc[4][4];
#pragma unroll
  for (int i = 0; i < 4; ++i)
#pragma unroll
    for (int j = 0; j < 4; ++j) acc[i][j] = (floatx4){0.f, 0.f, 0.f, 0.f};

  for (int kt = 0; kt < K; kt += BK) {
#pragma unroll
    for (int p = 0; p < 2; ++p) {
      const int arow = p * 64 + w * 16;
      long gA;
      if (MODE == 0) {
        gA = (long)(bm + arow + lrow) * K + kt + lcol;
      } else {
        const int m = bm + arow + lrow;
        const int b = m >> 11, t = m & 2047;
        const int k0 = kt + lcol;
        const int head = k0 >> 6, dd = k0 & 63;
        gA = (((long)(b * N_HEAD + head)) * SEQ + t) * HEAD_DIM + dd;
      }
      __builtin_amdgcn_global_load_lds((ga_t*)(A + gA), (la_t*)&As[arow * BK],
                                       16, 0, 0);
      const long gB = (long)(bn + arow + lrow) * K + kt + lcol;
      __builtin_amdgcn_global_load_lds((ga_t*)(Bt + gB), (la_t*)&Bs[arow * BK],
                                       16, 0, 0);
    }
    __syncthreads();

    bf16x8 af[4], bfr[4];
#pragma unroll
    for (int i = 0; i < 4; ++i)
      af[i] = __builtin_bit_cast(
          bf16x8, *(const u16x8*)&As[(wm + i * 16 + m16) * BK + quad * 8]);
#pragma unroll
    for (int j = 0; j < 4; ++j)
      bfr[j] = __builtin_bit_cast(
          bf16x8, *(const u16x8*)&Bs[(wn + j * 16 + m16) * BK + quad * 8]);
#pragma unroll
    for (int i = 0; i < 4; ++i)
#pragma unroll
      for (int j = 0; j < 4; ++j)
        acc[i][j] = __builtin_amdgcn_mfma_f32_16x16x32_bf16(af[i], bfr[j],
                                                            acc[i][j], 0, 0, 0);
    __syncthreads();
  }

#pragma unroll
  for (int i = 0; i < 4; ++i) {
#pragma unroll
    for (int j = 0; j < 4; ++j) {
      const int col = bn + wn + j * 16 + m16;
      const float bv = bias[col];
      if (MODE == 1) {
#pragma unroll
        for (int r = 0; r < 4; ++r) {
          const int row = bm + wm + i * 16 + quad * 4 + r;
          out[(long)row * N_EMBD + col] = acc[i][j][r] + bv;
        }
      } else {
        const int which = col >> 10;  // 0=q 1=k 2=v (wave-uniform)
        const int cc = col & 1023;
        const int h = cc >> 6;
        const int dd = cc & 63;
        const int row0 = bm + wm + i * 16 + quad * 4;
        const int b = row0 >> 11;
        const int t0 = row0 & 2047;
        if (which == 2) {
          // vT[B,H,D,T]: 4 consecutive t -> one 8B store
          u16x4 pk;
#pragma unroll
          for (int r = 0; r < 4; ++r) pk[r] = f2bf(acc[i][j][r] + bv);
          *(u16x4*)&vo[(((long)(b * N_HEAD + h)) * HEAD_DIM + dd) * SEQ + t0] =
              pk;
        } else {
          u16* dst = (which == 0) ? qo : ko;
#pragma unroll
          for (int r = 0; r < 4; ++r)
            dst[(((long)(b * N_HEAD + h)) * SEQ + t0 + r) * HEAD_DIM + dd] =
                f2bf(acc[i][j][r] + bv);
        }
      }
    }
  }
}

// ======== flash attention — S^T formulation, vT input ========
#define BQ 64
#define BKV 64
#define KPAD 72
#define LOG2E 1.44269504f
#define NQT (SEQ / BQ)  // 32 q-tiles

__device__ __forceinline__ void load_kv(const u16* __restrict__ K,
                                        const u16* __restrict__ Vt, long bh,
                                        int kt, int tid, u16x8 kreg[2],
                                        u16x8 vreg[2]) {
#pragma unroll
  for (int i = 0; i < 2; ++i) {
    const int p = tid + 256 * i;
    const int kkey = p >> 3, kdg = p & 7;
    kreg[i] = *(const u16x8*)&K[(bh * SEQ + kt + kkey) * HEAD_DIM + kdg * 8];
    const int vd = p >> 3, vkg = (p & 7) * 8;  // Vt row d, 8 keys
    vreg[i] = *(const u16x8*)&Vt[(bh * HEAD_DIM + vd) * SEQ + kt + vkg];
  }
}

__global__ __launch_bounds__(256) void flash_attn(u16* __restrict__ Qy,
                                                  const u16* __restrict__ K,
                                                  const u16* __restrict__ Vt) {
  const int pidx = blockIdx.x;  // 0..15
  const int h = blockIdx.y;
  const int b = blockIdx.z;
  const long bh = b * N_HEAD + h;
  const int tid = threadIdx.x;
  const int w = tid >> 6;
  const int l = tid & 63;
  const int m16 = l & 15;
  const int quad = l >> 4;

  __shared__ u16 Kl[2][BKV * KPAD];       // [buf][key][d]
  __shared__ u16 Vl[2][HEAD_DIM * KPAD];  // [buf][d][key]
  __shared__ u16 Pl[4][16 * KPAD];        // per-wave [q][key]

  const float SC = 0.125f * LOG2E;

  for (int ph = 0; ph < 2; ++ph) {
    const int iq = (ph == 0) ? pidx : (NQT - 1 - pidx);
    const int qb = iq * BQ;
    const int ntiles = iq + 1;
    const int qglob = qb + w * 16 + m16;

    bf16x8 qf[2];
    {
      const u16* qrow = Qy + (bh * SEQ + qglob) * HEAD_DIM;
      qf[0] = __builtin_bit_cast(bf16x8, *(const u16x8*)&qrow[quad * 8]);
      qf[1] = __builtin_bit_cast(bf16x8, *(const u16x8*)&qrow[32 + quad * 8]);
    }

    floatx4 Oacc[4];  // O^T: col=q=m16, row=d = t*16 + quad*4 + r
#pragma unroll
    for (int t = 0; t < 4; ++t) Oacc[t] = (floatx4){0.f, 0.f, 0.f, 0.f};
    float mrow = -1e30f, lrow = 0.f;

    u16x8 kreg[2], vreg[2];
    load_kv(K, Vt, bh, 0, tid, kreg, vreg);

    for (int it = 0; it < ntiles; ++it) {
      const int buf = it & 1;
#pragma unroll
      for (int i = 0; i < 2; ++i) {
        const int p = tid + 256 * i;
        const int kkey = p >> 3, kdg = p & 7;
        *(u16x8*)&Kl[buf][kkey * KPAD + kdg * 8] = kreg[i];
        const int vd = p >> 3, vkg = (p & 7) * 8;
        *(u16x8*)&Vl[buf][vd * KPAD + vkg] = vreg[i];
      }
      __syncthreads();
      if (it + 1 < ntiles) load_kv(K, Vt, bh, (it + 1) * BKV, tid, kreg, vreg);

      // ---- S^T = K Q^T (raw scores; scale folded into exp FMA) ----
      floatx4 s[4];
#pragma unroll
      for (int j = 0; j < 4; ++j) s[j] = (floatx4){0.f, 0.f, 0.f, 0.f};
#pragma unroll
      for (int j = 0; j < 4; ++j)
#pragma unroll
        for (int kk = 0; kk < 2; ++kk) {
          const bf16x8 kf = __builtin_bit_cast(
              bf16x8, *(const u16x8*)&Kl[buf][(j * 16 + m16) * KPAD + kk * 32 +
                                              quad * 8]);
          s[j] = __builtin_amdgcn_mfma_f32_16x16x32_bf16(kf, qf[kk], s[j], 0,
                                                         0, 0);
        }
      if (it == ntiles - 1) {
        const int kt = it * BKV;
#pragma unroll
        for (int j = 0; j < 4; ++j) {
          const int key0 = kt + j * 16 + quad * 4;
#pragma unroll
          for (int r = 0; r < 4; ++r)
            if (key0 + r > qglob) s[j][r] = -1e30f;
        }
      }

      // ---- online softmax: raw max -> scaled space via one mul ----
      float tm = s[0][0];
#pragma unroll
      for (int j = 0; j < 4; ++j)
#pragma unroll
        for (int r = 0; r < 4; ++r) tm = fmaxf(tm, s[j][r]);
      tm = fmaxf(tm, __shfl_xor(tm, 16, 64));
      tm = fmaxf(tm, __shfl_xor(tm, 32, 64));
      const float mn = fmaxf(mrow, tm * SC);
      const float al = EXP2(mrow - mn);
      mrow = mn;

      float ls = 0.f;
#pragma unroll
      for (int j = 0; j < 4; ++j) {
        u16x4 pk;
#pragma unroll
        for (int r = 0; r < 4; ++r) {
          const float p = EXP2(__builtin_fmaf(s[j][r], SC, -mn));
          ls += p;
          pk[r] = f2bf(p);
        }
        *(u16x4*)&Pl[w][m16 * KPAD + j * 16 + quad * 4] = pk;
      }
      ls += __shfl_xor(ls, 16, 64);
      ls += __shfl_xor(ls, 32, 64);
      lrow = lrow * al + ls;
#pragma unroll
      for (int t = 0; t < 4; ++t)
#pragma unroll
        for (int r = 0; r < 4; ++r) Oacc[t][r] *= al;

      // ---- O^T += V^T P^T ----
      bf16x8 pf[2];
      pf[0] = __builtin_bit_cast(bf16x8,
                                 *(const u16x8*)&Pl[w][m16 * KPAD + quad * 8]);
      pf[1] = __builtin_bit_cast(
          bf16x8, *(const u16x8*)&Pl[w][m16 * KPAD + 32 + quad * 8]);
#pragma unroll
      for (int t = 0; t < 4; ++t)
#pragma unroll
        for (int kk = 0; kk < 2; ++kk) {
          const bf16x8 vf = __builtin_bit_cast(
              bf16x8, *(const u16x8*)&Vl[buf][(t * 16 + m16) * KPAD + kk * 32 +
                                              quad * 8]);
          Oacc[t] = __builtin_amdgcn_mfma_f32_16x16x32_bf16(vf, pf[kk],
                                                            Oacc[t], 0, 0, 0);
        }
    }

    // ---- epilogue: O^T lane holds (d = t*16+quad*4+r, q = m16) ----
    const float invl = 1.f / lrow;
#pragma unroll
    for (int t = 0; t < 4; ++t) {
      u16x4 pk;
#pragma unroll
      for (int r = 0; r < 4; ++r) pk[r] = f2bf(Oacc[t][r] * invl);
      *(u16x4*)&Qy[(bh * SEQ + qglob) * HEAD_DIM + t * 16 + quad * 4] = pk;
    }
    __syncthreads();  // phase B reuses LDS buffers
  }
}

// ======== launch ========
extern "C" void kernel_launch(void* const* d_in, const int* in_sizes, int n_in,
                              void* d_out, int out_size, void* d_ws,
                              size_t ws_size, hipStream_t stream) {
  const float* x = (const float*)d_in[0];
  const float* w_attn = (const float*)d_in[1];
  const float* b_attn = (const float*)d_in[2];
  const float* w_proj = (const float*)d_in[3];
  const float* b_proj = (const float*)d_in[4];
  float* out = (float*)d_out;

  // ws: q 8 | k 8 | vT 8 | wT_a 6 | wT_p 2 | xb 8  = 40 MB
  char* ws = (char*)d_ws;
  const size_t SZ = (size_t)BATCH * N_HEAD * SEQ * HEAD_DIM * sizeof(u16);
  u16* q = (u16*)(ws);
  u16* k = (u16*)(ws + SZ);
  u16* vT = (u16*)(ws + 2 * SZ);
  u16* wT_a = (u16*)(ws + 3 * SZ);
  u16* wT_p = (u16*)(ws + 3 * SZ + (size_t)3 * N_EMBD * N_EMBD * sizeof(u16));
  u16* xb = (u16*)(ws + 3 * SZ + (size_t)4 * N_EMBD * N_EMBD * sizeof(u16));

  convert_x<<<(long)M_ROWS * N_EMBD / 8 / 256, 256, 0, stream>>>(x, xb);
  transpose2<<<dim3(128, 32), dim3(32, 8), 0, stream>>>(w_attn, w_proj, wT_a,
                                                        wT_p);

  gemm128<0><<<dim3(3 * N_EMBD / 128, M_ROWS / 128), 256, 0, stream>>>(
      xb, wT_a, b_attn, nullptr, q, k, vT, 3 * N_EMBD, N_EMBD);

  flash_attn<<<dim3(NQT / 2, N_HEAD, BATCH), 256, 0, stream>>>(q, k, vT);

  gemm128<1><<<dim3(N_EMBD / 128, M_ROWS / 128), 256, 0, stream>>>(
      q, wT_p, b_proj, out, nullptr, nullptr, nullptr, N_EMBD, N_EMBD);
}

// Round 11
// 188.429 us; speedup vs baseline: 17.1263x; 1.0471x over previous
//
#include <hip/hip_runtime.h>

typedef unsigned short u16;
typedef u16 u16x4 __attribute__((ext_vector_type(4)));
typedef u16 u16x8 __attribute__((ext_vector_type(8)));
typedef __bf16 bf16x8 __attribute__((ext_vector_type(8)));
typedef float floatx4 __attribute__((ext_vector_type(4)));

#define N_EMBD 1024
#define N_HEAD 16
#define HEAD_DIM 64
#define SEQ 2048
#define BATCH 2
#define M_ROWS (BATCH * SEQ)  // 4096

typedef __attribute__((address_space(1))) const unsigned char ga_t;
typedef __attribute__((address_space(3))) unsigned char la_t;

#if __has_builtin(__builtin_amdgcn_exp2f)
#define EXP2(x) __builtin_amdgcn_exp2f(x)
#else
#define EXP2(x) exp2f(x)
#endif

// native gfx950 f32->bf16 (RNE), 1 instr
__device__ __forceinline__ u16 cvt_bf16(float f) {
  return __builtin_bit_cast(u16, (__bf16)f);
}

// ======== prep: convert x (blocks 0..2047) + transpose both weights ========
__global__ __launch_bounds__(256) void prep(const float* __restrict__ x,
                                            u16* __restrict__ xb,
                                            const float* __restrict__ wa,
                                            const float* __restrict__ wp,
                                            u16* __restrict__ outa,
                                            u16* __restrict__ outp) {
  const int bid = blockIdx.x;
  if (bid < 2048) {  // convert_x
    const long i = ((long)bid * 256 + threadIdx.x) * 8;
    const float4 f0 = *(const float4*)&x[i];
    const float4 f1 = *(const float4*)&x[i + 4];
    u16x8 p;
    p[0] = cvt_bf16(f0.x); p[1] = cvt_bf16(f0.y);
    p[2] = cvt_bf16(f0.z); p[3] = cvt_bf16(f0.w);
    p[4] = cvt_bf16(f1.x); p[5] = cvt_bf16(f1.y);
    p[6] = cvt_bf16(f1.z); p[7] = cvt_bf16(f1.w);
    *(u16x8*)&xb[i] = p;
    return;
  }
  // transpose: linearized (gx 0..127, gy 0..31); gx<96: w_attn, else w_proj
  __shared__ u16 tile[32][33];
  const int t = bid - 2048;
  const int gx = t & 127;
  const int gy = t >> 7;
  const int R = N_EMBD;
  const float* in;
  u16* out;
  int C, bx;
  if (gx < 96) {
    in = wa; out = outa; C = 3 * N_EMBD; bx = gx * 32;
  } else {
    in = wp; out = outp; C = N_EMBD; bx = (gx - 96) * 32;
  }
  const int by = gy * 32;
  const int tx = threadIdx.x & 31;
  const int ty = threadIdx.x >> 5;
#pragma unroll
  for (int j = 0; j < 32; j += 8)
    tile[ty + j][tx] = cvt_bf16(in[(long)(by + ty + j) * C + bx + tx]);
  __syncthreads();
#pragma unroll
  for (int j = 0; j < 32; j += 8)
    out[(long)(bx + ty + j) * R + by + tx] = tile[tx][ty + j];
}

// ======== 128x128 GEMM, m97-style global_load_lds staging ========
// MODE 0: A=xb [M,K]; epilogue scatters q/k (bf16 [B,H,T,D]) and vT [B,H,D,T].
// MODE 1: A=q-buffer remap; epilogue writes fp32 out + bias.
#define BK 32

template <int MODE>
__global__ __launch_bounds__(256) void gemm128(
    const u16* __restrict__ A, const u16* __restrict__ Bt,
    const float* __restrict__ bias, float* __restrict__ out,
    u16* __restrict__ qo, u16* __restrict__ ko, u16* __restrict__ vo, int N,
    int K) {
  __shared__ u16 As[128 * BK];
  __shared__ u16 Bs[128 * BK];
  const int tid = threadIdx.x;
  const int bm = blockIdx.y * 128;
  const int bn = blockIdx.x * 128;
  const int w = tid >> 6;
  const int l = tid & 63;
  const int wm = (w >> 1) * 64;
  const int wn = (w & 1) * 64;
  const int m16 = l & 15;
  const int quad = l >> 4;
  const int lrow = l >> 2;
  const int lcol = (l & 3) * 8;

  floatx4 acc[4][4];
#pragma unroll
  for (int i = 0; i < 4; ++i)
#pragma unroll
    for (int j = 0; j < 4; ++j) acc[i][j] = (floatx4){0.f, 0.f, 0.f, 0.f};

  for (int kt = 0; kt < K; kt += BK) {
#pragma unroll
    for (int p = 0; p < 2; ++p) {
      const int arow = p * 64 + w * 16;
      long gA;
      if (MODE == 0) {
        gA = (long)(bm + arow + lrow) * K + kt + lcol;
      } else {
        const int m = bm + arow + lrow;
        const int b = m >> 11, t = m & 2047;
        const int k0 = kt + lcol;
        const int head = k0 >> 6, dd = k0 & 63;
        gA = (((long)(b * N_HEAD + head)) * SEQ + t) * HEAD_DIM + dd;
      }
      __builtin_amdgcn_global_load_lds((ga_t*)(A + gA), (la_t*)&As[arow * BK],
                                       16, 0, 0);
      const long gB = (long)(bn + arow + lrow) * K + kt + lcol;
      __builtin_amdgcn_global_load_lds((ga_t*)(Bt + gB), (la_t*)&Bs[arow * BK],
                                       16, 0, 0);
    }
    __syncthreads();

    bf16x8 af[4], bfr[4];
#pragma unroll
    for (int i = 0; i < 4; ++i)
      af[i] = __builtin_bit_cast(
          bf16x8, *(const u16x8*)&As[(wm + i * 16 + m16) * BK + quad * 8]);
#pragma unroll
    for (int j = 0; j < 4; ++j)
      bfr[j] = __builtin_bit_cast(
          bf16x8, *(const u16x8*)&Bs[(wn + j * 16 + m16) * BK + quad * 8]);
#pragma unroll
    for (int i = 0; i < 4; ++i)
#pragma unroll
      for (int j = 0; j < 4; ++j)
        acc[i][j] = __builtin_amdgcn_mfma_f32_16x16x32_bf16(af[i], bfr[j],
                                                            acc[i][j], 0, 0, 0);
    __syncthreads();
  }

#pragma unroll
  for (int i = 0; i < 4; ++i) {
#pragma unroll
    for (int j = 0; j < 4; ++j) {
      const int col = bn + wn + j * 16 + m16;
      const float bv = bias[col];
      if (MODE == 1) {
#pragma unroll
        for (int r = 0; r < 4; ++r) {
          const int row = bm + wm + i * 16 + quad * 4 + r;
          out[(long)row * N_EMBD + col] = acc[i][j][r] + bv;
        }
      } else {
        const int which = col >> 10;  // 0=q 1=k 2=v (wave-uniform)
        const int cc = col & 1023;
        const int h = cc >> 6;
        const int dd = cc & 63;
        const int row0 = bm + wm + i * 16 + quad * 4;
        const int b = row0 >> 11;
        const int t0 = row0 & 2047;
        if (which == 2) {
          u16x4 pk;
#pragma unroll
          for (int r = 0; r < 4; ++r) pk[r] = cvt_bf16(acc[i][j][r] + bv);
          *(u16x4*)&vo[(((long)(b * N_HEAD + h)) * HEAD_DIM + dd) * SEQ + t0] =
              pk;
        } else {
          u16* dst = (which == 0) ? qo : ko;
#pragma unroll
          for (int r = 0; r < 4; ++r)
            dst[(((long)(b * N_HEAD + h)) * SEQ + t0 + r) * HEAD_DIM + dd] =
                cvt_bf16(acc[i][j][r] + bv);
        }
      }
    }
  }
}

// ======== flash attention — S^T, un-paired grid + XCD-affine swizzle ======
// 1024 blocks, one q-tile each. id = (31-iq)*32 | (bh>>3)*8 | (bh&7):
// heavy tiles dispatch first (load balance); all blocks of one (b,h) share
// id%8 -> same XCD under round-robin -> KV stays in that XCD's L2 (2MB/XCD).
#define BQ 64
#define BKV 64
#define KPAD 72
#define LOG2E 1.44269504f
#define NQT (SEQ / BQ)  // 32 q-tiles

__device__ __forceinline__ void load_kv(const u16* __restrict__ K,
                                        const u16* __restrict__ Vt, long bh,
                                        int kt, int tid, u16x8 kreg[2],
                                        u16x8 vreg[2]) {
#pragma unroll
  for (int i = 0; i < 2; ++i) {
    const int p = tid + 256 * i;
    const int kkey = p >> 3, kdg = p & 7;
    kreg[i] = *(const u16x8*)&K[(bh * SEQ + kt + kkey) * HEAD_DIM + kdg * 8];
    const int vd = p >> 3, vkg = (p & 7) * 8;  // Vt row d, 8 keys
    vreg[i] = *(const u16x8*)&Vt[(bh * HEAD_DIM + vd) * SEQ + kt + vkg];
  }
}

__global__ __launch_bounds__(256) void flash_attn(u16* __restrict__ Qy,
                                                  const u16* __restrict__ K,
                                                  const u16* __restrict__ Vt) {
  const int id = blockIdx.x;
  const int iq = (NQT - 1) - (id >> 5);
  const int bh_ = ((id >> 3) & 3) * 8 + (id & 7);
  const long bh = bh_;
  const int tid = threadIdx.x;
  const int w = tid >> 6;
  const int l = tid & 63;
  const int m16 = l & 15;
  const int quad = l >> 4;

  __shared__ u16 Kl[2][BKV * KPAD];       // [buf][key][d]
  __shared__ u16 Vl[2][HEAD_DIM * KPAD];  // [buf][d][key]
  __shared__ u16 Pl[4][16 * KPAD];        // per-wave [q][key]

  const float SC = 0.125f * LOG2E;

  const int qb = iq * BQ;
  const int ntiles = iq + 1;
  const int qglob = qb + w * 16 + m16;

  bf16x8 qf[2];
  {
    const u16* qrow = Qy + (bh * SEQ + qglob) * HEAD_DIM;
    qf[0] = __builtin_bit_cast(bf16x8, *(const u16x8*)&qrow[quad * 8]);
    qf[1] = __builtin_bit_cast(bf16x8, *(const u16x8*)&qrow[32 + quad * 8]);
  }

  floatx4 Oacc[4];  // O^T: col=q=m16, row=d = t*16 + quad*4 + r
#pragma unroll
  for (int t = 0; t < 4; ++t) Oacc[t] = (floatx4){0.f, 0.f, 0.f, 0.f};
  float mrow = -1e30f, lrow = 0.f;

  u16x8 kreg[2], vreg[2];
  load_kv(K, Vt, bh, 0, tid, kreg, vreg);

  for (int it = 0; it < ntiles; ++it) {
    const int buf = it & 1;
#pragma unroll
    for (int i = 0; i < 2; ++i) {
      const int p = tid + 256 * i;
      const int kkey = p >> 3, kdg = p & 7;
      *(u16x8*)&Kl[buf][kkey * KPAD + kdg * 8] = kreg[i];
      const int vd = p >> 3, vkg = (p & 7) * 8;
      *(u16x8*)&Vl[buf][vd * KPAD + vkg] = vreg[i];
    }
    __syncthreads();
    if (it + 1 < ntiles) load_kv(K, Vt, bh, (it + 1) * BKV, tid, kreg, vreg);

    // ---- S^T = K Q^T (raw scores; scale folded into exp FMA) ----
    floatx4 s[4];
#pragma unroll
    for (int j = 0; j < 4; ++j) s[j] = (floatx4){0.f, 0.f, 0.f, 0.f};
#pragma unroll
    for (int j = 0; j < 4; ++j)
#pragma unroll
      for (int kk = 0; kk < 2; ++kk) {
        const bf16x8 kf = __builtin_bit_cast(
            bf16x8, *(const u16x8*)&Kl[buf][(j * 16 + m16) * KPAD + kk * 32 +
                                            quad * 8]);
        s[j] = __builtin_amdgcn_mfma_f32_16x16x32_bf16(kf, qf[kk], s[j], 0, 0,
                                                       0);
      }
    if (it == ntiles - 1) {
      const int kt = it * BKV;
#pragma unroll
      for (int j = 0; j < 4; ++j) {
        const int key0 = kt + j * 16 + quad * 4;
#pragma unroll
        for (int r = 0; r < 4; ++r)
          if (key0 + r > qglob) s[j][r] = -1e30f;
      }
    }

    // ---- online softmax ----
    float tm = s[0][0];
#pragma unroll
    for (int j = 0; j < 4; ++j)
#pragma unroll
      for (int r = 0; r < 4; ++r) tm = fmaxf(tm, s[j][r]);
    tm = fmaxf(tm, __shfl_xor(tm, 16, 64));
    tm = fmaxf(tm, __shfl_xor(tm, 32, 64));
    const float mn = fmaxf(mrow, tm * SC);
    const float al = EXP2(mrow - mn);
    mrow = mn;

    float ls = 0.f;
#pragma unroll
    for (int j = 0; j < 4; ++j) {
      u16x4 pk;
#pragma unroll
      for (int r = 0; r < 4; ++r) {
        const float p = EXP2(__builtin_fmaf(s[j][r], SC, -mn));
        ls += p;
        pk[r] = cvt_bf16(p);
      }
      *(u16x4*)&Pl[w][m16 * KPAD + j * 16 + quad * 4] = pk;
    }
    ls += __shfl_xor(ls, 16, 64);
    ls += __shfl_xor(ls, 32, 64);
    lrow = lrow * al + ls;
#pragma unroll
    for (int t = 0; t < 4; ++t)
#pragma unroll
      for (int r = 0; r < 4; ++r) Oacc[t][r] *= al;

    // ---- O^T += V^T P^T ----
    bf16x8 pf[2];
    pf[0] = __builtin_bit_cast(bf16x8,
                               *(const u16x8*)&Pl[w][m16 * KPAD + quad * 8]);
    pf[1] = __builtin_bit_cast(
        bf16x8, *(const u16x8*)&Pl[w][m16 * KPAD + 32 + quad * 8]);
#pragma unroll
    for (int t = 0; t < 4; ++t)
#pragma unroll
      for (int kk = 0; kk < 2; ++kk) {
        const bf16x8 vf = __builtin_bit_cast(
            bf16x8, *(const u16x8*)&Vl[buf][(t * 16 + m16) * KPAD + kk * 32 +
                                            quad * 8]);
        Oacc[t] = __builtin_amdgcn_mfma_f32_16x16x32_bf16(vf, pf[kk], Oacc[t],
                                                          0, 0, 0);
      }
  }

  // ---- epilogue: O^T lane holds (d = t*16+quad*4+r, q = m16) ----
  const float invl = 1.f / lrow;
#pragma unroll
  for (int t = 0; t < 4; ++t) {
    u16x4 pk;
#pragma unroll
    for (int r = 0; r < 4; ++r) pk[r] = cvt_bf16(Oacc[t][r] * invl);
    *(u16x4*)&Qy[(bh * SEQ + qglob) * HEAD_DIM + t * 16 + quad * 4] = pk;
  }
}

// ======== launch ========
extern "C" void kernel_launch(void* const* d_in, const int* in_sizes, int n_in,
                              void* d_out, int out_size, void* d_ws,
                              size_t ws_size, hipStream_t stream) {
  const float* x = (const float*)d_in[0];
  const float* w_attn = (const float*)d_in[1];
  const float* b_attn = (const float*)d_in[2];
  const float* w_proj = (const float*)d_in[3];
  const float* b_proj = (const float*)d_in[4];
  float* out = (float*)d_out;

  // ws: q 8 | k 8 | vT 8 | wT_a 6 | wT_p 2 | xb 8  = 40 MB
  char* ws = (char*)d_ws;
  const size_t SZ = (size_t)BATCH * N_HEAD * SEQ * HEAD_DIM * sizeof(u16);
  u16* q = (u16*)(ws);
  u16* k = (u16*)(ws + SZ);
  u16* vT = (u16*)(ws + 2 * SZ);
  u16* wT_a = (u16*)(ws + 3 * SZ);
  u16* wT_p = (u16*)(ws + 3 * SZ + (size_t)3 * N_EMBD * N_EMBD * sizeof(u16));
  u16* xb = (u16*)(ws + 3 * SZ + (size_t)4 * N_EMBD * N_EMBD * sizeof(u16));

  prep<<<2048 + 4096, 256, 0, stream>>>(x, xb, w_attn, w_proj, wT_a, wT_p);

  gemm128<0><<<dim3(3 * N_EMBD / 128, M_ROWS / 128), 256, 0, stream>>>(
      xb, wT_a, b_attn, nullptr, q, k, vT, 3 * N_EMBD, N_EMBD);

  flash_attn<<<NQT * 32, 256, 0, stream>>>(q, k, vT);

  gemm128<1><<<dim3(N_EMBD / 128, M_ROWS / 128), 256, 0, stream>>>(
      q, wT_p, b_proj, out, nullptr, nullptr, nullptr, N_EMBD, N_EMBD);
}